// Round 6
// baseline (178.299 us; speedup 1.0000x reference)
//
#include <hip/hip_runtime.h>
#include <cstdint>
#include <cstddef>

#define B_     128
#define N_TOK  196
#define D_IN   768
#define K_SEL  144
#define P_     2000
#define PPAD   2048
#define C_     192
#define NC_    200
#define RPB    160            // padded rows per batch: 1 cls + 144 sel + 15 pad
#define M_PAD  (B_ * RPB)     // 20480 = 256 * 80
#define ROWS   80             // rows per mlp_fused block (5 m-frags)
#define EPS_   1e-4f
#define KC_    100            // k-chunk for final_partial (4000 = 40*100)
#define NKC    40
#define BT_    8              // batch-tile for final_partial (128 = 16*8)

typedef __bf16 bf16;
typedef bf16 bf16x8 __attribute__((ext_vector_type(8)));
typedef bf16 bf16x4 __attribute__((ext_vector_type(4)));
typedef float f32x4 __attribute__((ext_vector_type(4)));

#define MFMA(a, b, c) __builtin_amdgcn_mfma_f32_16x16x32_bf16(a, b, c, 0, 0, 0)

__device__ __forceinline__ void gload_lds16(const void* g, void* l) {
  __builtin_amdgcn_global_load_lds(
      (const __attribute__((address_space(1))) unsigned int*)g,
      (__attribute__((address_space(3))) unsigned int*)l, 16, 0, 0);
}

// ---------------------------------------------------------------------------
// top-K (stable, lower-index-wins like lax.top_k) -> absolute x_tokens row per
// padded slot: slot 0 = cls, 1..144 = sorted selected, 145..159 = -1.
// ---------------------------------------------------------------------------
__global__ __launch_bounds__(256) void topk_rowidx(const float* __restrict__ attn,
                                                   int* __restrict__ rowidx) {
  __shared__ float av[N_TOK];
  __shared__ int   flag[N_TOK];
  int b = blockIdx.x, t = threadIdx.x;
  if (t < N_TOK) av[t] = attn[b * N_TOK + t];
  __syncthreads();
  if (t < N_TOK) {
    float v = av[t];
    int rank = 0;
    for (int j = 0; j < N_TOK; ++j) {
      float u = av[j];
      rank += (u > v || (u == v && j < t)) ? 1 : 0;
    }
    flag[t] = (rank < K_SEL) ? 1 : 0;
  }
  __syncthreads();
  if (t == 0) rowidx[b * RPB] = b * (N_TOK + 1);
  if (t < RPB - (K_SEL + 1)) rowidx[b * RPB + K_SEL + 1 + t] = -1;
  if (t < N_TOK && flag[t]) {
    int pos = 0;
    for (int j = 0; j < t; ++j) pos += flag[j];
    rowidx[b * RPB + 1 + pos] = b * (N_TOK + 1) + 1 + t;
  }
}

// ---------------------------------------------------------------------------
// Fused f32 -> bf16 convert for all 4 weights + proto_local (zero-padded tail).
// ---------------------------------------------------------------------------
#define SEG1 73728     // 384*768/4
#define SEG2 36864     // 384*384/4
#define SEG3 18432     // 192*384/4
#define SEG4 9216      // 192*192/4
#define SEG5 98304     // PPAD*C_/4
#define CVT_TOT (SEG1 + SEG2 + SEG3 + SEG4 + SEG5)  // 236544

__global__ __launch_bounds__(256) void cvt_all(
    const float* __restrict__ w1, const float* __restrict__ w2,
    const float* __restrict__ w3, const float* __restrict__ w4,
    const float* __restrict__ pl,
    bf16* __restrict__ w1b, bf16* __restrict__ w2b,
    bf16* __restrict__ w3b, bf16* __restrict__ w4b,
    bf16* __restrict__ plb) {
  int i4 = blockIdx.x * 256 + threadIdx.x;
  if (i4 >= CVT_TOT) return;
  const float* s; bf16* d; int nv; int base;
  if (i4 < SEG1)                       { s = w1; d = w1b; nv = 384 * 768; base = i4; }
  else if (i4 < SEG1 + SEG2)           { s = w2; d = w2b; nv = 384 * 384; base = i4 - SEG1; }
  else if (i4 < SEG1 + SEG2 + SEG3)    { s = w3; d = w3b; nv = 192 * 384; base = i4 - (SEG1 + SEG2); }
  else if (i4 < SEG1 + SEG2 + SEG3 + SEG4) { s = w4; d = w4b; nv = 192 * 192; base = i4 - (SEG1 + SEG2 + SEG3); }
  else                                 { s = pl; d = plb; nv = P_ * C_; base = i4 - (SEG1 + SEG2 + SEG3 + SEG4); }
  int i = base * 4;
  bf16x4 o;
#pragma unroll
  for (int j = 0; j < 4; ++j)
    o[j] = (i + j < nv) ? (bf16)s[i + j] : (bf16)0.f;
  *reinterpret_cast<bf16x4*>(d + i) = o;
}

// ---------------------------------------------------------------------------
// MFMA helper for mlp_fused: one BK=64 step, 5 m-frags x 3 n-frags.
// A tile = [80][64] swizzled, W tile = [192][64] swizzled.
// ---------------------------------------------------------------------------
__device__ __forceinline__ void mfma_step(const char* Abase, const char* Wbase,
                                          int wn, int l15, int lhi,
                                          f32x4 acc[5][3]) {
#pragma unroll
  for (int kk = 0; kk < 2; ++kk) {
    bf16x8 bfr[3];
#pragma unroll
    for (int nf = 0; nf < 3; ++nf) {
      int rr = wn + nf * 16 + l15;
      int c = kk * 4 + lhi;
      bfr[nf] = *reinterpret_cast<const bf16x8*>(Wbase + (rr * 8 + (c ^ (rr & 7))) * 16);
    }
#pragma unroll
    for (int mf = 0; mf < 5; ++mf) {
      int rr = mf * 16 + l15;
      int c = kk * 4 + lhi;
      bf16x8 afr = *reinterpret_cast<const bf16x8*>(Abase + (rr * 8 + (c ^ (rr & 7))) * 16);
#pragma unroll
      for (int nf = 0; nf < 3; ++nf)
        acc[mf][nf] = MFMA(afr, bfr[nf], acc[mf][nf]);
    }
  }
}

// Epilogue: bias + act, store bf16 into swizzled [kt][ROWS][64] LDS layout.
__device__ __forceinline__ void epi_store(f32x4 acc[5][3], const float* bias,
                                          int pc0, int wn, int l15, int lhi,
                                          char* Hout, int act) {
#pragma unroll
  for (int mf = 0; mf < 5; ++mf)
#pragma unroll
    for (int nf = 0; nf < 3; ++nf) {
      int col = pc0 + wn + nf * 16 + l15;
      float bv = bias[col];
      int kt2 = col >> 6, kc = col & 63;
#pragma unroll
      for (int q = 0; q < 4; ++q) {
        int row = mf * 16 + lhi * 4 + q;
        float v = acc[mf][nf][q] + bv;
        v = (act == 0) ? fmaxf(v, 0.f) : 1.f / (1.f + expf(-v));
        *reinterpret_cast<bf16*>(Hout +
            ((kt2 * ROWS + row) * 8 + ((kc >> 3) ^ (row & 7))) * 16 +
            (kc & 7) * 2) = (bf16)v;
      }
    }
}

// ---------------------------------------------------------------------------
// Fused 4-layer MLP: gathers x_tokens rows (f32->bf16) on the fly, keeps all
// intermediates in LDS, writes F (bf16) + fnorm to global. 256 blocks (1/CU),
// 256 threads (4 waves, each owning a 48-col slice of a 192-col pass).
// Layers: 768->384 (2 passes), 384->384 (2 passes), 384->192, 192->192(sigm).
// ---------------------------------------------------------------------------
__global__ __launch_bounds__(256) void mlp_fused(
    const float* __restrict__ x, const int* __restrict__ rowidx,
    const bf16* __restrict__ w1b, const float* __restrict__ b1,
    const bf16* __restrict__ w2b, const float* __restrict__ b2,
    const bf16* __restrict__ w3b, const float* __restrict__ b3,
    const bf16* __restrict__ w4b, const float* __restrict__ b4,
    bf16* __restrict__ Fb, float* __restrict__ fnorm) {
  __shared__ __align__(16) bf16 H0[ROWS * 384];    // 61440 B
  __shared__ __align__(16) bf16 H1s[ROWS * 384];   // 61440 B
  __shared__ __align__(16) bf16 Wst[192 * 64];     // 24576 B
  __shared__ __align__(16) bf16 Ast[ROWS * 64];    // 10240 B
  __shared__ int ridx[ROWS];
  const int bm = blockIdx.x * ROWS;
  const int tid = threadIdx.x;
  const int lane = tid & 63;
  const int wn = (tid >> 6) * 48;
  const int l15 = lane & 15, lhi = lane >> 4;
  if (tid < ROWS) ridx[tid] = rowidx[bm + tid];
  __syncthreads();

  // ---- Layer 1: K=768, N=384, gathered f32 input, 2 column passes
  for (int p = 0; p < 2; ++p) {
    const int pc0 = p * 192;
    f32x4 acc[5][3] = {};
    for (int kt = 0; kt < 12; ++kt) {
      const int k0 = kt * 64;
      // reg-stage A tile (gather + cvt), swizzled ds_write
#pragma unroll
      for (int i = 0; i < 5; ++i) {
        int idx = i * 256 + tid;          // 1280 float4-quads
        int r = idx >> 4, q = idx & 15;
        int src = ridx[r];
        bf16x4 o4;
        if (src >= 0) {
          float4 v = *reinterpret_cast<const float4*>(x + (size_t)src * D_IN + k0 + q * 4);
          o4[0] = (bf16)v.x; o4[1] = (bf16)v.y; o4[2] = (bf16)v.z; o4[3] = (bf16)v.w;
        } else {
          o4[0] = (bf16)0.f; o4[1] = (bf16)0.f; o4[2] = (bf16)0.f; o4[3] = (bf16)0.f;
        }
        int byte = (r * 8 + (((q >> 1)) ^ (r & 7))) * 16 + (q & 1) * 8;
        *reinterpret_cast<bf16x4*>((char*)Ast + byte) = o4;
      }
      // stage W1 tile [192][64]
#pragma unroll
      for (int i = 0; i < 6; ++i) {
        int o = i * 256 + tid;
        int r = o >> 3, cb = o & 7;
        int gc = (cb ^ (r & 7)) * 8;
        gload_lds16(w1b + (size_t)(pc0 + r) * 768 + k0 + gc, (char*)Wst + o * 16);
      }
      __syncthreads();
      mfma_step((const char*)Ast, (const char*)Wst, wn, l15, lhi, acc);
      __syncthreads();
    }
    epi_store(acc, b1, pc0, wn, l15, lhi, (char*)H0, 0);
  }
  __syncthreads();

  // ---- Layer 2: K=384, N=384, in H0, out H1s, 2 passes
  for (int p = 0; p < 2; ++p) {
    const int pc0 = p * 192;
    f32x4 acc[5][3] = {};
    for (int kt = 0; kt < 6; ++kt) {
#pragma unroll
      for (int i = 0; i < 6; ++i) {
        int o = i * 256 + tid;
        int r = o >> 3, cb = o & 7;
        int gc = (cb ^ (r & 7)) * 8;
        gload_lds16(w2b + (size_t)(pc0 + r) * 384 + kt * 64 + gc, (char*)Wst + o * 16);
      }
      __syncthreads();
      mfma_step((const char*)H0 + kt * (ROWS * 128), (const char*)Wst, wn, l15, lhi, acc);
      __syncthreads();
    }
    epi_store(acc, b2, pc0, wn, l15, lhi, (char*)H1s, 0);
  }
  __syncthreads();

  // ---- Layer 3: K=384, N=192, in H1s, out H0
  {
    f32x4 acc[5][3] = {};
    for (int kt = 0; kt < 6; ++kt) {
#pragma unroll
      for (int i = 0; i < 6; ++i) {
        int o = i * 256 + tid;
        int r = o >> 3, cb = o & 7;
        int gc = (cb ^ (r & 7)) * 8;
        gload_lds16(w3b + (size_t)r * 384 + kt * 64 + gc, (char*)Wst + o * 16);
      }
      __syncthreads();
      mfma_step((const char*)H1s + kt * (ROWS * 128), (const char*)Wst, wn, l15, lhi, acc);
      __syncthreads();
    }
    epi_store(acc, b3, 0, wn, l15, lhi, (char*)H0, 0);
  }
  __syncthreads();

  // ---- Layer 4: K=192, N=192, in H0, out H1s (sigmoid)
  {
    f32x4 acc[5][3] = {};
    for (int kt = 0; kt < 3; ++kt) {
#pragma unroll
      for (int i = 0; i < 6; ++i) {
        int o = i * 256 + tid;
        int r = o >> 3, cb = o & 7;
        int gc = (cb ^ (r & 7)) * 8;
        gload_lds16(w4b + (size_t)r * 192 + kt * 64 + gc, (char*)Wst + o * 16);
      }
      __syncthreads();
      mfma_step((const char*)H0 + kt * (ROWS * 128), (const char*)Wst, wn, l15, lhi, acc);
      __syncthreads();
    }
    epi_store(acc, b4, 0, wn, l15, lhi, (char*)H1s, 1);
  }
  __syncthreads();

  // ---- F writeout (coalesced bf16x8) + fused fnorm
#pragma unroll
  for (int i = 0; i < 8; ++i) {
    int o = i * 256 + tid;                 // 1920 granules total
    if (o < ROWS * 24) {
      int kt = o / (ROWS * 8);
      int rem = o - kt * (ROWS * 8);
      int r = rem >> 3, gc = rem & 7;
      bf16x8 vv = *reinterpret_cast<const bf16x8*>(
          (const char*)H1s + ((kt * ROWS + r) * 8 + (gc ^ (r & 7))) * 16);
      *reinterpret_cast<bf16x8*>(Fb + (size_t)(bm + r) * C_ + kt * 64 + gc * 8) = vv;
    }
  }
  if (tid < ROWS) {
    float s = 0.f;
    for (int kt = 0; kt < 3; ++kt)
#pragma unroll
      for (int g = 0; g < 8; ++g) {
        bf16x8 vv = *reinterpret_cast<const bf16x8*>(
            (const char*)H1s + ((kt * ROWS + tid) * 8 + (g ^ (tid & 7))) * 16);
#pragma unroll
        for (int j = 0; j < 8; ++j) { float f = (float)vv[j]; s += f * f; }
      }
    fnorm[bm + tid] = s;
  }
}

// ---------------------------------------------------------------------------
// Prototype norms: rows 0..2047 = plb (bf16) -> pnl; 2048..4047 = proto_g
// (f32) -> png.
// ---------------------------------------------------------------------------
__global__ __launch_bounds__(256) void pnorms(
    const bf16* __restrict__ plb, const float* __restrict__ pg,
    float* __restrict__ pnl, float* __restrict__ png) {
  int m = blockIdx.x * 4 + (threadIdx.x >> 6);
  int lane = threadIdx.x & 63;
  float s = 0.f;
  if (m < PPAD) {
    const bf16* f = plb + (size_t)m * C_;
#pragma unroll
    for (int k = 0; k < 3; ++k) { float v = (float)f[lane + k * 64]; s += v * v; }
  } else if (m < PPAD + P_) {
    const float* f = pg + (size_t)(m - PPAD) * C_;
#pragma unroll
    for (int k = 0; k < 3; ++k) { float v = f[lane + k * 64]; s += v * v; }
  } else return;
  for (int o = 32; o > 0; o >>= 1) s += __shfl_down(s, o, 64);
  if (lane == 0) {
    if (m < PPAD) pnl[m] = s; else png[m - PPAD] = s;
  }
}

// ---------------------------------------------------------------------------
// Per-batch distance + min-over-tokens + log activation, bf16 MFMA.
// ---------------------------------------------------------------------------
__global__ __launch_bounds__(256, 2) void dist_img_mfma(
    const bf16* __restrict__ F, const bf16* __restrict__ P,
    const float* __restrict__ fnorm, const float* __restrict__ pnorm,
    float* __restrict__ act_l) {
  __shared__ __align__(16) bf16 Fs[160 * 64];
  __shared__ __align__(16) bf16 Ps[128 * 64];
  __shared__ float fn[RPB];
  const int b = blockIdx.y;
  const int p0 = blockIdx.x * 128;
  const int tid = threadIdx.x;
  const int lane = tid & 63, wid = tid >> 6;
  const int wn = wid * 32;
  const int l15 = lane & 15, lhi = lane >> 4;
  if (tid < RPB) fn[tid] = fnorm[b * RPB + tid];
  f32x4 acc[10][2] = {};
  for (int k0 = 0; k0 < C_; k0 += 64) {
#pragma unroll
    for (int i = 0; i < 5; ++i) {
      int o = i * 256 + tid;
      int r = o >> 3, cb = o & 7;
      int gc = (cb ^ (r & 7)) * 8;
      gload_lds16(F + (size_t)(b * RPB + r) * C_ + k0 + gc, (char*)Fs + o * 16);
    }
#pragma unroll
    for (int i = 0; i < 4; ++i) {
      int o = i * 256 + tid;
      int r = o >> 3, cb = o & 7;
      int gc = (cb ^ (r & 7)) * 8;
      gload_lds16(P + (size_t)(p0 + r) * C_ + k0 + gc, (char*)Ps + o * 16);
    }
    __syncthreads();
#pragma unroll
    for (int kk = 0; kk < 2; ++kk) {
      bf16x8 bfr[2];
#pragma unroll
      for (int nf = 0; nf < 2; ++nf) {
        int rr = wn + nf * 16 + l15;
        int c = kk * 4 + lhi;
        bfr[nf] = *reinterpret_cast<const bf16x8*>(
            (const char*)Ps + (rr * 8 + (c ^ (rr & 7))) * 16);
      }
#pragma unroll
      for (int mf = 0; mf < 10; ++mf) {
        int rr = mf * 16 + l15;
        int c = kk * 4 + lhi;
        bf16x8 afr = *reinterpret_cast<const bf16x8*>(
            (const char*)Fs + (rr * 8 + (c ^ (rr & 7))) * 16);
#pragma unroll
        for (int nf = 0; nf < 2; ++nf)
          acc[mf][nf] = MFMA(afr, bfr[nf], acc[mf][nf]);
      }
    }
    __syncthreads();
  }
#pragma unroll
  for (int nf = 0; nf < 2; ++nf) {
    float mn = 3.4e38f;
#pragma unroll
    for (int mf = 0; mf < 10; ++mf)
#pragma unroll
      for (int q = 0; q < 4; ++q) {
        int row = mf * 16 + lhi * 4 + q;
        float e = fn[row] - 2.f * acc[mf][nf][q];
        if (row >= 1 && row <= K_SEL) mn = fminf(mn, e);
      }
    mn = fminf(mn, __shfl_xor(mn, 16, 64));
    mn = fminf(mn, __shfl_xor(mn, 32, 64));
    int p = p0 + wn + nf * 16 + l15;
    if (lhi == 0 && p < P_) {
      float d = fmaxf(mn + pnorm[p], 0.f);
      act_l[(size_t)b * P_ + p] = logf((d + 1.f) / (d + EPS_));
    }
  }
}

// ---------------------------------------------------------------------------
// CLS distances vs proto_global (f32 protos, bf16 cls feature rows).
// ---------------------------------------------------------------------------
__global__ __launch_bounds__(256) void dist_cls(
    const bf16* __restrict__ F, const float* __restrict__ proto,
    const float* __restrict__ fnorm, const float* __restrict__ pnorm,
    float* __restrict__ act_g) {
  int i = blockIdx.x * 256 + threadIdx.x;  // 128*2000 threads exactly
  int b = i / P_, p = i - b * P_;
  const bf16* f = F + (size_t)(b * RPB) * C_;
  const float* pr = proto + (size_t)p * C_;
  float dot = 0.f;
  for (int k = 0; k < C_; k += 8) {
    bf16x8 fv = *reinterpret_cast<const bf16x8*>(f + k);
    float4 p0 = *reinterpret_cast<const float4*>(pr + k);
    float4 p1 = *reinterpret_cast<const float4*>(pr + k + 4);
    dot += (float)fv[0] * p0.x + (float)fv[1] * p0.y + (float)fv[2] * p0.z +
           (float)fv[3] * p0.w + (float)fv[4] * p1.x + (float)fv[5] * p1.y +
           (float)fv[6] * p1.z + (float)fv[7] * p1.w;
  }
  float d = fmaxf(fnorm[b * RPB] - 2.f * dot + pnorm[p], 0.f);
  act_g[i] = logf((d + 1.f) / (d + EPS_));
}

// ---------------------------------------------------------------------------
// Final stage:
// prep_wt: wT2[c][k] = k<2000 ? 0.3*lwg[c][k] : 0.7*lw[c][k-2000]  (200x4000)
// final_partial: part[kc][b][c] = sum_{k in chunk} act[b][k] * wT2[c][k]
// final_reduce:  out[b][c] = sum_kc part[kc][b][c]
// ---------------------------------------------------------------------------
__global__ __launch_bounds__(256) void prep_wt(const float* __restrict__ lwg,
                                               const float* __restrict__ lw,
                                               float* __restrict__ wT2) {
  int i = blockIdx.x * 256 + threadIdx.x;
  if (i >= NC_ * 4000) return;
  int c = i / 4000, k = i - c * 4000;
  float v = (k < 2000) ? 0.3f * lwg[(size_t)c * 2000 + k]
                       : 0.7f * lw[(size_t)c * 2000 + (k - 2000)];
  wT2[i] = v;
}

__global__ __launch_bounds__(256) void final_partial(
    const float* __restrict__ actg, const float* __restrict__ actl,
    const float* __restrict__ wT2, float* __restrict__ part) {
  __shared__ __align__(16) float sa[KC_][BT_];
  const int kc = blockIdx.x;   // 0..39
  const int bt = blockIdx.y;   // 0..15
  const int t = threadIdx.x;
  const int b0 = bt * BT_;
  const int kg0 = kc * KC_;
  const float* act = (kg0 < 2000) ? actg : actl;
  const int koff = (kg0 < 2000) ? kg0 : kg0 - 2000;
  for (int i = t; i < KC_ * BT_; i += 256) {
    int b = i / KC_;
    int k = i - b * KC_;
    sa[k][b] = act[(size_t)(b0 + b) * P_ + koff + k];
  }
  __syncthreads();
  const int c = t;
  if (c >= NC_) return;
  float acc[BT_] = {};
  const float4* w4p = reinterpret_cast<const float4*>(wT2 + (size_t)c * 4000 + kg0);
#pragma unroll 5
  for (int k4 = 0; k4 < KC_ / 4; ++k4) {
    float4 w4 = w4p[k4];
    float wv[4] = {w4.x, w4.y, w4.z, w4.w};
#pragma unroll
    for (int j = 0; j < 4; ++j) {
      float w = wv[j];
      const float4* s4 = reinterpret_cast<const float4*>(&sa[k4 * 4 + j][0]);
      float4 a0 = s4[0], a1 = s4[1];
      acc[0] += w * a0.x; acc[1] += w * a0.y; acc[2] += w * a0.z; acc[3] += w * a0.w;
      acc[4] += w * a1.x; acc[5] += w * a1.y; acc[6] += w * a1.z; acc[7] += w * a1.w;
    }
  }
#pragma unroll
  for (int b = 0; b < BT_; ++b)
    part[((size_t)kc * B_ + b0 + b) * NC_ + c] = acc[b];
}

__global__ __launch_bounds__(256) void final_reduce(const float* __restrict__ part,
                                                    float* __restrict__ out) {
  int i = blockIdx.x * 256 + threadIdx.x;
  if (i >= B_ * NC_) return;
  float s = 0.f;
#pragma unroll 8
  for (int kc = 0; kc < NKC; ++kc) s += part[(size_t)kc * (B_ * NC_) + i];
  out[i] = s;
}

// ---------------------------------------------------------------------------
extern "C" void kernel_launch(void* const* d_in, const int* in_sizes, int n_in,
                              void* d_out, int out_size, void* d_ws, size_t ws_size,
                              hipStream_t stream) {
  const float* x_tokens = (const float*)d_in[0];
  const float* attn     = (const float*)d_in[1];
  const float* w1 = (const float*)d_in[2];
  const float* b1 = (const float*)d_in[3];
  const float* w2 = (const float*)d_in[4];
  const float* b2 = (const float*)d_in[5];
  const float* w3 = (const float*)d_in[6];
  const float* b3 = (const float*)d_in[7];
  const float* w4 = (const float*)d_in[8];
  const float* b4 = (const float*)d_in[9];
  const float* proto_l = (const float*)d_in[10];
  const float* proto_g = (const float*)d_in[11];
  const float* last_w  = (const float*)d_in[12];
  const float* last_wg = (const float*)d_in[13];
  float* out = (float*)d_out;

  char* wsb = (char*)d_ws;
  auto alloc = [&](size_t bytes) {
    char* p = wsb;
    wsb += (bytes + 255) & ~(size_t)255;
    return p;
  };
  bf16* w1b = (bf16*)alloc((size_t)384 * 768 * sizeof(bf16));
  bf16* w2b = (bf16*)alloc((size_t)384 * 384 * sizeof(bf16));
  bf16* w3b = (bf16*)alloc((size_t)192 * 384 * sizeof(bf16));
  bf16* w4b = (bf16*)alloc((size_t)192 * 192 * sizeof(bf16));
  bf16* plb = (bf16*)alloc((size_t)PPAD * C_ * sizeof(bf16));
  bf16* Fb  = (bf16*)alloc((size_t)M_PAD * C_ * sizeof(bf16));    // 7.9 MB
  int*   rowidx = (int*)  alloc((size_t)M_PAD * sizeof(int));
  float* fnorm  = (float*)alloc((size_t)M_PAD * sizeof(float));
  float* pnl    = (float*)alloc((size_t)PPAD * sizeof(float));
  float* png    = (float*)alloc((size_t)P_ * sizeof(float));
  float* actg   = (float*)alloc((size_t)B_ * P_ * sizeof(float));
  float* actl   = (float*)alloc((size_t)B_ * P_ * sizeof(float));
  float* wT2    = (float*)alloc((size_t)NC_ * 4000 * sizeof(float));
  float* part   = (float*)alloc((size_t)NKC * B_ * NC_ * sizeof(float));

  topk_rowidx<<<B_, 256, 0, stream>>>(attn, rowidx);

  cvt_all<<<(CVT_TOT + 255) / 256, 256, 0, stream>>>(w1, w2, w3, w4, proto_l,
                                                     w1b, w2b, w3b, w4b, plb);

  mlp_fused<<<M_PAD / ROWS, 256, 0, stream>>>(x_tokens, rowidx,
                                              w1b, b1, w2b, b2, w3b, b3, w4b, b4,
                                              Fb, fnorm);

  prep_wt<<<(NC_ * 4000 + 255) / 256, 256, 0, stream>>>(last_wg, last_w, wT2);

  pnorms<<<(PPAD + P_ + 3) / 4, 256, 0, stream>>>(plb, proto_g, pnl, png);

  dist_img_mfma<<<dim3(PPAD / 128, B_), 256, 0, stream>>>(Fb, plb, fnorm, pnl, actl);
  dist_cls<<<(B_ * P_) / 256, 256, 0, stream>>>(Fb, proto_g, fnorm, png, actg);

  final_partial<<<dim3(NKC, B_ / BT_), 256, 0, stream>>>(actg, actl, wT2, part);
  final_reduce<<<(B_ * NC_ + 255) / 256, 256, 0, stream>>>(part, out);
}

// Round 7
// 162.354 us; speedup vs baseline: 1.0982x; 1.0982x over previous
//
#include <hip/hip_runtime.h>
#include <cstdint>
#include <cstddef>

#define B_     128
#define N_TOK  196
#define D_IN   768
#define K_SEL  144
#define P_     2000
#define PPAD   2048
#define C_     192
#define NC_    200
#define RPB    160            // padded rows per batch: 1 cls + 144 sel + 15 pad
#define M_PAD  (B_ * RPB)     // 20480
#define EPS_   1e-4f
#define KC_    100            // k-chunk for final_partial (4000 = 40*100)
#define NKC    40
#define BT_    8              // batch-tile for final_partial (128 = 16*8)

typedef __bf16 bf16;
typedef bf16 bf16x8 __attribute__((ext_vector_type(8)));
typedef bf16 bf16x4 __attribute__((ext_vector_type(4)));
typedef float f32x4 __attribute__((ext_vector_type(4)));

#define MFMA(a, b, c) __builtin_amdgcn_mfma_f32_16x16x32_bf16(a, b, c, 0, 0, 0)

__device__ __forceinline__ void gload_lds16(const void* g, void* l) {
  __builtin_amdgcn_global_load_lds(
      (const __attribute__((address_space(1))) unsigned int*)g,
      (__attribute__((address_space(3))) unsigned int*)l, 16, 0, 0);
}

// ---------------------------------------------------------------------------
// Prologue: blocks 0..127 = per-batch top-K (stable, lower-index-wins) ->
// rowidx; blocks 128.. = fused f32->bf16 convert of 4 weights + proto_local.
// ---------------------------------------------------------------------------
#define SEG1 73728     // 384*768/4
#define SEG2 36864     // 384*384/4
#define SEG3 18432     // 192*384/4
#define SEG4 9216      // 192*192/4
#define SEG5 98304     // PPAD*C_/4
#define CVT_TOT (SEG1 + SEG2 + SEG3 + SEG4 + SEG5)  // 236544 = 924*256

__global__ __launch_bounds__(256) void prologue(
    const float* __restrict__ attn, int* __restrict__ rowidx,
    const float* __restrict__ w1, const float* __restrict__ w2,
    const float* __restrict__ w3, const float* __restrict__ w4,
    const float* __restrict__ pl,
    bf16* __restrict__ w1b, bf16* __restrict__ w2b,
    bf16* __restrict__ w3b, bf16* __restrict__ w4b,
    bf16* __restrict__ plb) {
  if (blockIdx.x < B_) {
    __shared__ float av[N_TOK];
    __shared__ int   flag[N_TOK];
    int b = blockIdx.x, t = threadIdx.x;
    if (t < N_TOK) av[t] = attn[b * N_TOK + t];
    __syncthreads();
    if (t < N_TOK) {
      float v = av[t];
      int rank = 0;
      for (int j = 0; j < N_TOK; ++j) {
        float u = av[j];
        rank += (u > v || (u == v && j < t)) ? 1 : 0;
      }
      flag[t] = (rank < K_SEL) ? 1 : 0;
    }
    __syncthreads();
    if (t == 0) rowidx[b * RPB] = b * (N_TOK + 1);
    if (t < RPB - (K_SEL + 1)) rowidx[b * RPB + K_SEL + 1 + t] = -1;
    if (t < N_TOK && flag[t]) {
      int pos = 0;
      for (int j = 0; j < t; ++j) pos += flag[j];
      rowidx[b * RPB + 1 + pos] = b * (N_TOK + 1) + 1 + t;
    }
    return;
  }
  int i4 = (blockIdx.x - B_) * 256 + threadIdx.x;
  if (i4 >= CVT_TOT) return;
  const float* s; bf16* d; int nv; int base;
  if (i4 < SEG1)                       { s = w1; d = w1b; nv = 384 * 768; base = i4; }
  else if (i4 < SEG1 + SEG2)           { s = w2; d = w2b; nv = 384 * 384; base = i4 - SEG1; }
  else if (i4 < SEG1 + SEG2 + SEG3)    { s = w3; d = w3b; nv = 192 * 384; base = i4 - (SEG1 + SEG2); }
  else if (i4 < SEG1 + SEG2 + SEG3 + SEG4) { s = w4; d = w4b; nv = 192 * 192; base = i4 - (SEG1 + SEG2 + SEG3); }
  else                                 { s = pl; d = plb; nv = P_ * C_; base = i4 - (SEG1 + SEG2 + SEG3 + SEG4); }
  int i = base * 4;
  bf16x4 o;
#pragma unroll
  for (int j = 0; j < 4; ++j)
    o[j] = (i + j < nv) ? (bf16)s[i + j] : (bf16)0.f;
  *reinterpret_cast<bf16x4*>(d + i) = o;
}

// ---------------------------------------------------------------------------
// bf16 MFMA GEMM: out[M_PAD,N] = act(A @ W^T + bias), bf16 out.
// BM=128, BN templated, BK=64. 4 waves (2x2), wave tile 64 x (BN/2).
// GATHER: A is f32 x_tokens, rows via rowidx, reg-staged cvt + swizzled
// ds_write (both-sides swizzle in-kernel). Else: bf16 A via global_load_lds
// with pre-swizzled source (rule #21).
// ---------------------------------------------------------------------------
template <int ACT, int BN, bool GATHER>
__global__ __launch_bounds__(256, 2) void gemm_bf16(
    const void* __restrict__ Av, const int* __restrict__ rowidx,
    const bf16* __restrict__ W, const float* __restrict__ bias,
    bf16* __restrict__ out, int N, int Kd) {
  constexpr int NF = BN / 32;            // N-frags per wave
  __shared__ __align__(16) bf16 As[128 * 64];
  __shared__ __align__(16) bf16 Bs[BN * 64];
  __shared__ int ridx[128];
  const int bm = blockIdx.x * 128, bn = blockIdx.y * BN;
  const int tid = threadIdx.x;
  const int lane = tid & 63, wid = tid >> 6;
  const int wm = (wid >> 1) * 64, wn = (wid & 1) * (BN / 2);
  const int l15 = lane & 15, lhi = lane >> 4;
  if (GATHER) {
    if (tid < 128) ridx[tid] = rowidx[bm + tid];
    __syncthreads();
  }
  f32x4 acc[4][NF] = {};
  for (int k0 = 0; k0 < Kd; k0 += 64) {
    if (GATHER) {
      const float* x = (const float*)Av;
#pragma unroll
      for (int i = 0; i < 8; ++i) {
        int idx = i * 256 + tid;          // 2048 float4-quads (128 rows x 16)
        int r = idx >> 4, q = idx & 15;
        int src = ridx[r];
        bf16x4 o4;
        if (src >= 0) {
          float4 v = *reinterpret_cast<const float4*>(x + (size_t)src * D_IN + k0 + q * 4);
          o4[0] = (bf16)v.x; o4[1] = (bf16)v.y; o4[2] = (bf16)v.z; o4[3] = (bf16)v.w;
        } else {
          o4[0] = (bf16)0.f; o4[1] = (bf16)0.f; o4[2] = (bf16)0.f; o4[3] = (bf16)0.f;
        }
        int byte = (r * 8 + ((q >> 1) ^ (r & 7))) * 16 + (q & 1) * 8;
        *reinterpret_cast<bf16x4*>((char*)As + byte) = o4;
      }
    } else {
      const bf16* A = (const bf16*)Av;
#pragma unroll
      for (int i = 0; i < 4; ++i) {
        int o = i * 256 + tid;
        int r = o >> 3, cb = o & 7;
        int gc = (cb ^ (r & 7)) * 8;
        gload_lds16(A + (size_t)(bm + r) * Kd + k0 + gc, (char*)As + o * 16);
      }
    }
#pragma unroll
    for (int i = 0; i < NF; ++i) {
      int o = i * 256 + tid;
      int r = o >> 3, cb = o & 7;
      int gc = (cb ^ (r & 7)) * 8;
      gload_lds16(W + (size_t)(bn + r) * Kd + k0 + gc, (char*)Bs + o * 16);
    }
    __syncthreads();
#pragma unroll
    for (int kk = 0; kk < 2; ++kk) {
      bf16x8 bfr[NF];
#pragma unroll
      for (int nf = 0; nf < NF; ++nf) {
        int rr = wn + nf * 16 + l15;
        int c = kk * 4 + lhi;
        bfr[nf] = *reinterpret_cast<const bf16x8*>(
            (const char*)Bs + (rr * 8 + (c ^ (rr & 7))) * 16);
      }
#pragma unroll
      for (int mf = 0; mf < 4; ++mf) {
        int rr = wm + mf * 16 + l15;
        int c = kk * 4 + lhi;
        bf16x8 afr = *reinterpret_cast<const bf16x8*>(
            (const char*)As + (rr * 8 + (c ^ (rr & 7))) * 16);
#pragma unroll
        for (int nf = 0; nf < NF; ++nf)
          acc[mf][nf] = MFMA(afr, bfr[nf], acc[mf][nf]);
      }
    }
    __syncthreads();
  }
#pragma unroll
  for (int mf = 0; mf < 4; ++mf)
#pragma unroll
    for (int nf = 0; nf < NF; ++nf) {
      int col = bn + wn + nf * 16 + l15;
      float bv = bias[col];
#pragma unroll
      for (int q = 0; q < 4; ++q) {
        int row = bm + wm + mf * 16 + lhi * 4 + q;
        float v = acc[mf][nf][q] + bv;
        v = (ACT == 0) ? fmaxf(v, 0.f) : 1.f / (1.f + expf(-v));
        out[(size_t)row * N + col] = (bf16)v;
      }
    }
}

// ---------------------------------------------------------------------------
// Mid kernel: blocks [0, NORM_BLKS) = norms (F rows -> fnorm, plb -> pnl,
// proto_g -> png); blocks [NORM_BLKS, ..) = prep_wt (wT2[c][k], float4).
// ---------------------------------------------------------------------------
#define NORM_BLKS ((M_PAD + PPAD + P_) / 4)          // 6132
#define PREP_Q    (NC_ * 4000 / 4)                   // 200000 float4s
#define PREP_BLKS ((PREP_Q + 255) / 256)             // 782

__global__ __launch_bounds__(256) void mid_k(
    const bf16* __restrict__ F, const bf16* __restrict__ plb,
    const float* __restrict__ pg, const float* __restrict__ lwg,
    const float* __restrict__ lw, float* __restrict__ fnorm,
    float* __restrict__ pnl, float* __restrict__ png,
    float* __restrict__ wT2) {
  if (blockIdx.x < NORM_BLKS) {
    int m = blockIdx.x * 4 + (threadIdx.x >> 6);
    int lane = threadIdx.x & 63;
    float s = 0.f;
    if (m < M_PAD) {
      const bf16* f = F + (size_t)m * C_;
#pragma unroll
      for (int k = 0; k < 3; ++k) { float v = (float)f[lane + k * 64]; s += v * v; }
    } else if (m < M_PAD + PPAD) {
      const bf16* f = plb + (size_t)(m - M_PAD) * C_;
#pragma unroll
      for (int k = 0; k < 3; ++k) { float v = (float)f[lane + k * 64]; s += v * v; }
    } else {
      const float* f = pg + (size_t)(m - M_PAD - PPAD) * C_;
#pragma unroll
      for (int k = 0; k < 3; ++k) { float v = f[lane + k * 64]; s += v * v; }
    }
    for (int o = 32; o > 0; o >>= 1) s += __shfl_down(s, o, 64);
    if (lane == 0) {
      if (m < M_PAD) fnorm[m] = s;
      else if (m < M_PAD + PPAD) pnl[m - M_PAD] = s;
      else png[m - M_PAD - PPAD] = s;
    }
    return;
  }
  int i4 = (blockIdx.x - NORM_BLKS) * 256 + threadIdx.x;
  if (i4 >= PREP_Q) return;
  int c = i4 / 1000, k4 = i4 - c * 1000;   // 1000 float4s per c-row
  float4 v;
  if (k4 < 500) {
    v = *reinterpret_cast<const float4*>(lwg + (size_t)c * 2000 + k4 * 4);
    v.x *= 0.3f; v.y *= 0.3f; v.z *= 0.3f; v.w *= 0.3f;
  } else {
    v = *reinterpret_cast<const float4*>(lw + (size_t)c * 2000 + (k4 - 500) * 4);
    v.x *= 0.7f; v.y *= 0.7f; v.z *= 0.7f; v.w *= 0.7f;
  }
  *reinterpret_cast<float4*>(wT2 + (size_t)i4 * 4) = v;
}

// ---------------------------------------------------------------------------
// Per-batch distance + min-over-tokens + log activation, bf16 MFMA.
// ---------------------------------------------------------------------------
__global__ __launch_bounds__(256, 2) void dist_img_mfma(
    const bf16* __restrict__ F, const bf16* __restrict__ P,
    const float* __restrict__ fnorm, const float* __restrict__ pnorm,
    float* __restrict__ act_l) {
  __shared__ __align__(16) bf16 Fs[160 * 64];
  __shared__ __align__(16) bf16 Ps[128 * 64];
  __shared__ float fn[RPB];
  const int b = blockIdx.y;
  const int p0 = blockIdx.x * 128;
  const int tid = threadIdx.x;
  const int lane = tid & 63, wid = tid >> 6;
  const int wn = wid * 32;
  const int l15 = lane & 15, lhi = lane >> 4;
  if (tid < RPB) fn[tid] = fnorm[b * RPB + tid];
  f32x4 acc[10][2] = {};
  for (int k0 = 0; k0 < C_; k0 += 64) {
#pragma unroll
    for (int i = 0; i < 5; ++i) {
      int o = i * 256 + tid;
      int r = o >> 3, cb = o & 7;
      int gc = (cb ^ (r & 7)) * 8;
      gload_lds16(F + (size_t)(b * RPB + r) * C_ + k0 + gc, (char*)Fs + o * 16);
    }
#pragma unroll
    for (int i = 0; i < 4; ++i) {
      int o = i * 256 + tid;
      int r = o >> 3, cb = o & 7;
      int gc = (cb ^ (r & 7)) * 8;
      gload_lds16(P + (size_t)(p0 + r) * C_ + k0 + gc, (char*)Ps + o * 16);
    }
    __syncthreads();
#pragma unroll
    for (int kk = 0; kk < 2; ++kk) {
      bf16x8 bfr[2];
#pragma unroll
      for (int nf = 0; nf < 2; ++nf) {
        int rr = wn + nf * 16 + l15;
        int c = kk * 4 + lhi;
        bfr[nf] = *reinterpret_cast<const bf16x8*>(
            (const char*)Ps + (rr * 8 + (c ^ (rr & 7))) * 16);
      }
#pragma unroll
      for (int mf = 0; mf < 10; ++mf) {
        int rr = mf * 16 + l15;
        int c = kk * 4 + lhi;
        bf16x8 afr = *reinterpret_cast<const bf16x8*>(
            (const char*)Fs + (rr * 8 + (c ^ (rr & 7))) * 16);
#pragma unroll
        for (int nf = 0; nf < 2; ++nf)
          acc[mf][nf] = MFMA(afr, bfr[nf], acc[mf][nf]);
      }
    }
    __syncthreads();
  }
#pragma unroll
  for (int nf = 0; nf < 2; ++nf) {
    float mn = 3.4e38f;
#pragma unroll
    for (int mf = 0; mf < 10; ++mf)
#pragma unroll
      for (int q = 0; q < 4; ++q) {
        int row = mf * 16 + lhi * 4 + q;
        float e = fn[row] - 2.f * acc[mf][nf][q];
        if (row >= 1 && row <= K_SEL) mn = fminf(mn, e);
      }
    mn = fminf(mn, __shfl_xor(mn, 16, 64));
    mn = fminf(mn, __shfl_xor(mn, 32, 64));
    int p = p0 + wn + nf * 16 + l15;
    if (lhi == 0 && p < P_) {
      float d = fmaxf(mn + pnorm[p], 0.f);
      act_l[(size_t)b * P_ + p] = logf((d + 1.f) / (d + EPS_));
    }
  }
}

// ---------------------------------------------------------------------------
// CLS distances vs proto_global (f32 protos, bf16 cls feature rows).
// ---------------------------------------------------------------------------
__global__ __launch_bounds__(256) void dist_cls(
    const bf16* __restrict__ F, const float* __restrict__ proto,
    const float* __restrict__ fnorm, const float* __restrict__ pnorm,
    float* __restrict__ act_g) {
  int i = blockIdx.x * 256 + threadIdx.x;  // 128*2000 threads exactly
  int b = i / P_, p = i - b * P_;
  const bf16* f = F + (size_t)(b * RPB) * C_;
  const float* pr = proto + (size_t)p * C_;
  float dot = 0.f;
  for (int k = 0; k < C_; k += 8) {
    bf16x8 fv = *reinterpret_cast<const bf16x8*>(f + k);
    float4 p0 = *reinterpret_cast<const float4*>(pr + k);
    float4 p1 = *reinterpret_cast<const float4*>(pr + k + 4);
    dot += (float)fv[0] * p0.x + (float)fv[1] * p0.y + (float)fv[2] * p0.z +
           (float)fv[3] * p0.w + (float)fv[4] * p1.x + (float)fv[5] * p1.y +
           (float)fv[6] * p1.z + (float)fv[7] * p1.w;
  }
  float d = fmaxf(fnorm[b * RPB] - 2.f * dot + pnorm[p], 0.f);
  act_g[i] = logf((d + 1.f) / (d + EPS_));
}

// ---------------------------------------------------------------------------
// final_partial: part[kc][b][c] = sum_{k in chunk} act[b][k] * wT2[c][k]
// final_reduce:  out[b][c] = sum_kc part[kc][b][c]
// ---------------------------------------------------------------------------
__global__ __launch_bounds__(256) void final_partial(
    const float* __restrict__ actg, const float* __restrict__ actl,
    const float* __restrict__ wT2, float* __restrict__ part) {
  __shared__ __align__(16) float sa[KC_][BT_];
  const int kc = blockIdx.x;   // 0..39
  const int bt = blockIdx.y;   // 0..15
  const int t = threadIdx.x;
  const int b0 = bt * BT_;
  const int kg0 = kc * KC_;
  const float* act = (kg0 < 2000) ? actg : actl;
  const int koff = (kg0 < 2000) ? kg0 : kg0 - 2000;
  for (int i = t; i < KC_ * BT_; i += 256) {
    int b = i / KC_;
    int k = i - b * KC_;
    sa[k][b] = act[(size_t)(b0 + b) * P_ + koff + k];
  }
  __syncthreads();
  const int c = t;
  if (c >= NC_) return;
  float acc[BT_] = {};
  const float4* w4p = reinterpret_cast<const float4*>(wT2 + (size_t)c * 4000 + kg0);
#pragma unroll 5
  for (int k4 = 0; k4 < KC_ / 4; ++k4) {
    float4 w4 = w4p[k4];
    float wv[4] = {w4.x, w4.y, w4.z, w4.w};
#pragma unroll
    for (int j = 0; j < 4; ++j) {
      float w = wv[j];
      const float4* s4 = reinterpret_cast<const float4*>(&sa[k4 * 4 + j][0]);
      float4 a0 = s4[0], a1 = s4[1];
      acc[0] += w * a0.x; acc[1] += w * a0.y; acc[2] += w * a0.z; acc[3] += w * a0.w;
      acc[4] += w * a1.x; acc[5] += w * a1.y; acc[6] += w * a1.z; acc[7] += w * a1.w;
    }
  }
#pragma unroll
  for (int b = 0; b < BT_; ++b)
    part[((size_t)kc * B_ + b0 + b) * NC_ + c] = acc[b];
}

__global__ __launch_bounds__(256) void final_reduce(const float* __restrict__ part,
                                                    float* __restrict__ out) {
  int i = blockIdx.x * 256 + threadIdx.x;
  if (i >= B_ * NC_) return;
  float s = 0.f;
#pragma unroll 8
  for (int kc = 0; kc < NKC; ++kc) s += part[(size_t)kc * (B_ * NC_) + i];
  out[i] = s;
}

// ---------------------------------------------------------------------------
extern "C" void kernel_launch(void* const* d_in, const int* in_sizes, int n_in,
                              void* d_out, int out_size, void* d_ws, size_t ws_size,
                              hipStream_t stream) {
  const float* x_tokens = (const float*)d_in[0];
  const float* attn     = (const float*)d_in[1];
  const float* w1 = (const float*)d_in[2];
  const float* b1 = (const float*)d_in[3];
  const float* w2 = (const float*)d_in[4];
  const float* b2 = (const float*)d_in[5];
  const float* w3 = (const float*)d_in[6];
  const float* b3 = (const float*)d_in[7];
  const float* w4 = (const float*)d_in[8];
  const float* b4 = (const float*)d_in[9];
  const float* proto_l = (const float*)d_in[10];
  const float* proto_g = (const float*)d_in[11];
  const float* last_w  = (const float*)d_in[12];
  const float* last_wg = (const float*)d_in[13];
  float* out = (float*)d_out;

  char* wsb = (char*)d_ws;
  auto alloc = [&](size_t bytes) {
    char* p = wsb;
    wsb += (bytes + 255) & ~(size_t)255;
    return p;
  };
  bf16* bufA = (bf16*)alloc((size_t)M_PAD * 384 * sizeof(bf16));  // H1 -> H3
  bf16* bufB = (bf16*)alloc((size_t)M_PAD * 384 * sizeof(bf16));  // H2 -> Fb
  bf16* w1b = (bf16*)alloc((size_t)384 * 768 * sizeof(bf16));
  bf16* w2b = (bf16*)alloc((size_t)384 * 384 * sizeof(bf16));
  bf16* w3b = (bf16*)alloc((size_t)192 * 384 * sizeof(bf16));
  bf16* w4b = (bf16*)alloc((size_t)192 * 192 * sizeof(bf16));
  bf16* plb = (bf16*)alloc((size_t)PPAD * C_ * sizeof(bf16));
  int*   rowidx = (int*)  alloc((size_t)M_PAD * sizeof(int));
  float* fnorm  = (float*)alloc((size_t)M_PAD * sizeof(float));
  float* pnl    = (float*)alloc((size_t)PPAD * sizeof(float));
  float* png    = (float*)alloc((size_t)P_ * sizeof(float));
  float* actg   = (float*)alloc((size_t)B_ * P_ * sizeof(float));
  float* actl   = (float*)alloc((size_t)B_ * P_ * sizeof(float));
  float* wT2    = (float*)alloc((size_t)NC_ * 4000 * sizeof(float));
  float* part   = (float*)alloc((size_t)NKC * B_ * NC_ * sizeof(float));

  bf16* H1 = bufA;   // [M_PAD][384]
  bf16* H2 = bufB;   // [M_PAD][384]
  bf16* H3 = bufA;   // [M_PAD][192]  (H1 dead after gemm2)
  bf16* Fb = bufB;   // [M_PAD][192]  (H2 dead after gemm3)

  prologue<<<B_ + CVT_TOT / 256, 256, 0, stream>>>(
      attn, rowidx, w1, w2, w3, w4, proto_l, w1b, w2b, w3b, w4b, plb);

  // L1: gather(x f32) -> bf16 in-kernel, BN=128
  gemm_bf16<0, 128, true><<<dim3(M_PAD / 128, 384 / 128), 256, 0, stream>>>(
      x_tokens, rowidx, w1b, b1, H1, 384, 768);
  gemm_bf16<0, 128, false><<<dim3(M_PAD / 128, 384 / 128), 256, 0, stream>>>(
      H1, nullptr, w2b, b2, H2, 384, 384);
  gemm_bf16<0, 64, false><<<dim3(M_PAD / 128, 192 / 64), 256, 0, stream>>>(
      H2, nullptr, w3b, b3, H3, 192, 384);
  gemm_bf16<1, 64, false><<<dim3(M_PAD / 128, 192 / 64), 256, 0, stream>>>(
      H3, nullptr, w4b, b4, Fb, 192, 192);

  mid_k<<<NORM_BLKS + PREP_BLKS, 256, 0, stream>>>(
      Fb, plb, proto_g, last_wg, last_w, fnorm, pnl, png, wT2);

  dist_img_mfma<<<dim3(PPAD / 128, B_), 256, 0, stream>>>(Fb, plb, fnorm, pnl, actl);
  dist_cls<<<(B_ * P_) / 256, 256, 0, stream>>>(Fb, proto_g, fnorm, png, actg);

  final_partial<<<dim3(NKC, B_ / BT_), 256, 0, stream>>>(actg, actl, wT2, part);
  final_reduce<<<(B_ * NC_ + 255) / 256, 256, 0, stream>>>(part, out);
}

// Round 8
// 149.436 us; speedup vs baseline: 1.1932x; 1.0864x over previous
//
#include <hip/hip_runtime.h>
#include <cstdint>
#include <cstddef>

#define B_     128
#define N_TOK  196
#define D_IN   768
#define K_SEL  144
#define P_     2000
#define PPAD   2048
#define C_     192
#define NC_    200
#define RPB    160            // padded rows per batch: 1 cls + 144 sel + 15 pad
#define M_PAD  (B_ * RPB)     // 20480
#define EPS_   1e-4f
#define KC_    100            // k-chunk for final_partial (4000 = 40*100)
#define NKC    40
#define BT_    8              // batch-tile for final_partial (128 = 16*8)

typedef __bf16 bf16;
typedef bf16 bf16x8 __attribute__((ext_vector_type(8)));
typedef bf16 bf16x4 __attribute__((ext_vector_type(4)));
typedef float f32x4 __attribute__((ext_vector_type(4)));

#define MFMA(a, b, c) __builtin_amdgcn_mfma_f32_16x16x32_bf16(a, b, c, 0, 0, 0)

__device__ __forceinline__ void gload_lds16(const void* g, void* l) {
  __builtin_amdgcn_global_load_lds(
      (const __attribute__((address_space(1))) unsigned int*)g,
      (__attribute__((address_space(3))) unsigned int*)l, 16, 0, 0);
}

// ---------------------------------------------------------------------------
// Prologue: blocks 0..127 = per-batch top-K (stable, lower-index-wins) ->
// rowidx; blocks 128.. = fused f32->bf16 convert of 4 weights + proto_local.
// ---------------------------------------------------------------------------
#define SEG1 73728     // 384*768/4
#define SEG2 36864     // 384*384/4
#define SEG3 18432     // 192*384/4
#define SEG4 9216      // 192*192/4
#define SEG5 98304     // PPAD*C_/4
#define CVT_TOT (SEG1 + SEG2 + SEG3 + SEG4 + SEG5)  // 236544 = 924*256

__global__ __launch_bounds__(256) void prologue(
    const float* __restrict__ attn, int* __restrict__ rowidx,
    const float* __restrict__ w1, const float* __restrict__ w2,
    const float* __restrict__ w3, const float* __restrict__ w4,
    const float* __restrict__ pl,
    bf16* __restrict__ w1b, bf16* __restrict__ w2b,
    bf16* __restrict__ w3b, bf16* __restrict__ w4b,
    bf16* __restrict__ plb) {
  if (blockIdx.x < B_) {
    __shared__ float av[N_TOK];
    __shared__ int   flag[N_TOK];
    int b = blockIdx.x, t = threadIdx.x;
    if (t < N_TOK) av[t] = attn[b * N_TOK + t];
    __syncthreads();
    if (t < N_TOK) {
      float v = av[t];
      int rank = 0;
      for (int j = 0; j < N_TOK; ++j) {
        float u = av[j];
        rank += (u > v || (u == v && j < t)) ? 1 : 0;
      }
      flag[t] = (rank < K_SEL) ? 1 : 0;
    }
    __syncthreads();
    if (t == 0) rowidx[b * RPB] = b * (N_TOK + 1);
    if (t < RPB - (K_SEL + 1)) rowidx[b * RPB + K_SEL + 1 + t] = -1;
    if (t < N_TOK && flag[t]) {
      int pos = 0;
      for (int j = 0; j < t; ++j) pos += flag[j];
      rowidx[b * RPB + 1 + pos] = b * (N_TOK + 1) + 1 + t;
    }
    return;
  }
  int i4 = (blockIdx.x - B_) * 256 + threadIdx.x;
  if (i4 >= CVT_TOT) return;
  const float* s; bf16* d; int nv; int base;
  if (i4 < SEG1)                       { s = w1; d = w1b; nv = 384 * 768; base = i4; }
  else if (i4 < SEG1 + SEG2)           { s = w2; d = w2b; nv = 384 * 384; base = i4 - SEG1; }
  else if (i4 < SEG1 + SEG2 + SEG3)    { s = w3; d = w3b; nv = 192 * 384; base = i4 - (SEG1 + SEG2); }
  else if (i4 < SEG1 + SEG2 + SEG3 + SEG4) { s = w4; d = w4b; nv = 192 * 192; base = i4 - (SEG1 + SEG2 + SEG3); }
  else                                 { s = pl; d = plb; nv = P_ * C_; base = i4 - (SEG1 + SEG2 + SEG3 + SEG4); }
  int i = base * 4;
  bf16x4 o;
#pragma unroll
  for (int j = 0; j < 4; ++j)
    o[j] = (i + j < nv) ? (bf16)s[i + j] : (bf16)0.f;
  *reinterpret_cast<bf16x4*>(d + i) = o;
}

// ---------------------------------------------------------------------------
// Gather selected token rows from x_tokens, convert f32 -> bf16.
// ---------------------------------------------------------------------------
__global__ __launch_bounds__(192) void gather_cvt(const float* __restrict__ x,
                                                  const int* __restrict__ rowidx,
                                                  bf16* __restrict__ A0) {
  int row = blockIdx.x;
  int src = rowidx[row];
  int t = threadIdx.x;
  bf16x4 o;
  if (src >= 0) {
    float4 v = *reinterpret_cast<const float4*>(x + (size_t)src * D_IN + t * 4);
    o[0] = (bf16)v.x; o[1] = (bf16)v.y; o[2] = (bf16)v.z; o[3] = (bf16)v.w;
  } else {
    o[0] = (bf16)0.f; o[1] = (bf16)0.f; o[2] = (bf16)0.f; o[3] = (bf16)0.f;
  }
  *reinterpret_cast<bf16x4*>(A0 + (size_t)row * D_IN + t * 4) = o;
}

// ---------------------------------------------------------------------------
// bf16 MFMA GEMM with 2-phase double-buffered prefetch (T3-minimum):
// stage(t+1) issued BEFORE compute(t); one __syncthreads per K-step (its
// vmcnt(0) drain completes stage(t+1); barrier protects buffer reuse).
// BM=128, BN templated, BK=64. 4 waves (2x2), wave tile 64 x (BN/2).
// LDS XOR-swizzled (16B granule) with pre-swizzled global source (rule #21).
// ---------------------------------------------------------------------------
template <int ACT, int BN>
__global__ __launch_bounds__(256, 2) void gemm_bf16(
    const bf16* __restrict__ A, const bf16* __restrict__ W,
    const float* __restrict__ bias, bf16* __restrict__ out, int N, int Kd) {
  constexpr int NF = BN / 32;            // N-frags per wave
  __shared__ __align__(16) bf16 As[2][128 * 64];
  __shared__ __align__(16) bf16 Bs[2][BN * 64];
  const int bm = blockIdx.x * 128, bn = blockIdx.y * BN;
  const int tid = threadIdx.x;
  const int lane = tid & 63, wid = tid >> 6;
  const int wm = (wid >> 1) * 64, wn = (wid & 1) * (BN / 2);
  const int l15 = lane & 15, lhi = lane >> 4;

  auto stage = [&](int buf, int k0) {
#pragma unroll
    for (int i = 0; i < 4; ++i) {
      int o = i * 256 + tid;
      int r = o >> 3, cb = o & 7;
      int gc = (cb ^ (r & 7)) * 8;
      gload_lds16(A + (size_t)(bm + r) * Kd + k0 + gc, (char*)As[buf] + o * 16);
    }
#pragma unroll
    for (int i = 0; i < NF; ++i) {
      int o = i * 256 + tid;
      int r = o >> 3, cb = o & 7;
      int gc = (cb ^ (r & 7)) * 8;
      gload_lds16(W + (size_t)(bn + r) * Kd + k0 + gc, (char*)Bs[buf] + o * 16);
    }
  };

  f32x4 acc[4][NF] = {};
  const int NT = Kd >> 6;
  stage(0, 0);
  __syncthreads();                         // drain stage(0)
  for (int kt = 0; kt < NT; ++kt) {
    if (kt + 1 < NT) stage((kt + 1) & 1, (kt + 1) * 64);
    const char* Ab = (const char*)As[kt & 1];
    const char* Bb = (const char*)Bs[kt & 1];
#pragma unroll
    for (int kk = 0; kk < 2; ++kk) {
      bf16x8 bfr[NF];
#pragma unroll
      for (int nf = 0; nf < NF; ++nf) {
        int rr = wn + nf * 16 + l15;
        int c = kk * 4 + lhi;
        bfr[nf] = *reinterpret_cast<const bf16x8*>(Bb + (rr * 8 + (c ^ (rr & 7))) * 16);
      }
#pragma unroll
      for (int mf = 0; mf < 4; ++mf) {
        int rr = wm + mf * 16 + l15;
        int c = kk * 4 + lhi;
        bf16x8 afr = *reinterpret_cast<const bf16x8*>(Ab + (rr * 8 + (c ^ (rr & 7))) * 16);
#pragma unroll
        for (int nf = 0; nf < NF; ++nf)
          acc[mf][nf] = MFMA(afr, bfr[nf], acc[mf][nf]);
      }
    }
    __syncthreads();                       // drains stage(kt+1); guards reuse
  }
#pragma unroll
  for (int mf = 0; mf < 4; ++mf)
#pragma unroll
    for (int nf = 0; nf < NF; ++nf) {
      int col = bn + wn + nf * 16 + l15;
      float bv = bias[col];
#pragma unroll
      for (int q = 0; q < 4; ++q) {
        int row = bm + wm + mf * 16 + lhi * 4 + q;
        float v = acc[mf][nf][q] + bv;
        v = (ACT == 0) ? fmaxf(v, 0.f) : 1.f / (1.f + expf(-v));
        out[(size_t)row * N + col] = (bf16)v;
      }
    }
}

// ---------------------------------------------------------------------------
// Mid kernel: blocks [0, NORM_BLKS) = norms; rest = prep_wt (wT2[c][k]).
// ---------------------------------------------------------------------------
#define NORM_BLKS ((M_PAD + PPAD + P_) / 4)          // 6132
#define PREP_Q    (NC_ * 4000 / 4)                   // 200000 float4s
#define PREP_BLKS ((PREP_Q + 255) / 256)             // 782

__global__ __launch_bounds__(256) void mid_k(
    const bf16* __restrict__ F, const bf16* __restrict__ plb,
    const float* __restrict__ pg, const float* __restrict__ lwg,
    const float* __restrict__ lw, float* __restrict__ fnorm,
    float* __restrict__ pnl, float* __restrict__ png,
    float* __restrict__ wT2) {
  if (blockIdx.x < NORM_BLKS) {
    int m = blockIdx.x * 4 + (threadIdx.x >> 6);
    int lane = threadIdx.x & 63;
    float s = 0.f;
    if (m < M_PAD) {
      const bf16* f = F + (size_t)m * C_;
#pragma unroll
      for (int k = 0; k < 3; ++k) { float v = (float)f[lane + k * 64]; s += v * v; }
    } else if (m < M_PAD + PPAD) {
      const bf16* f = plb + (size_t)(m - M_PAD) * C_;
#pragma unroll
      for (int k = 0; k < 3; ++k) { float v = (float)f[lane + k * 64]; s += v * v; }
    } else {
      const float* f = pg + (size_t)(m - M_PAD - PPAD) * C_;
#pragma unroll
      for (int k = 0; k < 3; ++k) { float v = f[lane + k * 64]; s += v * v; }
    }
    for (int o = 32; o > 0; o >>= 1) s += __shfl_down(s, o, 64);
    if (lane == 0) {
      if (m < M_PAD) fnorm[m] = s;
      else if (m < M_PAD + PPAD) pnl[m - M_PAD] = s;
      else png[m - M_PAD - PPAD] = s;
    }
    return;
  }
  int i4 = (blockIdx.x - NORM_BLKS) * 256 + threadIdx.x;
  if (i4 >= PREP_Q) return;
  int c = i4 / 1000, k4 = i4 - c * 1000;   // 1000 float4s per c-row
  float4 v;
  if (k4 < 500) {
    v = *reinterpret_cast<const float4*>(lwg + (size_t)c * 2000 + k4 * 4);
    v.x *= 0.3f; v.y *= 0.3f; v.z *= 0.3f; v.w *= 0.3f;
  } else {
    v = *reinterpret_cast<const float4*>(lw + (size_t)c * 2000 + (k4 - 500) * 4);
    v.x *= 0.7f; v.y *= 0.7f; v.z *= 0.7f; v.w *= 0.7f;
  }
  *reinterpret_cast<float4*>(wT2 + (size_t)i4 * 4) = v;
}

// ---------------------------------------------------------------------------
// Per-batch distance + min-over-tokens + log activation, bf16 MFMA.
// ---------------------------------------------------------------------------
__global__ __launch_bounds__(256, 2) void dist_img_mfma(
    const bf16* __restrict__ F, const bf16* __restrict__ P,
    const float* __restrict__ fnorm, const float* __restrict__ pnorm,
    float* __restrict__ act_l) {
  __shared__ __align__(16) bf16 Fs[160 * 64];
  __shared__ __align__(16) bf16 Ps[128 * 64];
  __shared__ float fn[RPB];
  const int b = blockIdx.y;
  const int p0 = blockIdx.x * 128;
  const int tid = threadIdx.x;
  const int lane = tid & 63, wid = tid >> 6;
  const int wn = wid * 32;
  const int l15 = lane & 15, lhi = lane >> 4;
  if (tid < RPB) fn[tid] = fnorm[b * RPB + tid];
  f32x4 acc[10][2] = {};
  for (int k0 = 0; k0 < C_; k0 += 64) {
#pragma unroll
    for (int i = 0; i < 5; ++i) {
      int o = i * 256 + tid;
      int r = o >> 3, cb = o & 7;
      int gc = (cb ^ (r & 7)) * 8;
      gload_lds16(F + (size_t)(b * RPB + r) * C_ + k0 + gc, (char*)Fs + o * 16);
    }
#pragma unroll
    for (int i = 0; i < 4; ++i) {
      int o = i * 256 + tid;
      int r = o >> 3, cb = o & 7;
      int gc = (cb ^ (r & 7)) * 8;
      gload_lds16(P + (size_t)(p0 + r) * C_ + k0 + gc, (char*)Ps + o * 16);
    }
    __syncthreads();
#pragma unroll
    for (int kk = 0; kk < 2; ++kk) {
      bf16x8 bfr[2];
#pragma unroll
      for (int nf = 0; nf < 2; ++nf) {
        int rr = wn + nf * 16 + l15;
        int c = kk * 4 + lhi;
        bfr[nf] = *reinterpret_cast<const bf16x8*>(
            (const char*)Ps + (rr * 8 + (c ^ (rr & 7))) * 16);
      }
#pragma unroll
      for (int mf = 0; mf < 10; ++mf) {
        int rr = mf * 16 + l15;
        int c = kk * 4 + lhi;
        bf16x8 afr = *reinterpret_cast<const bf16x8*>(
            (const char*)Fs + (rr * 8 + (c ^ (rr & 7))) * 16);
#pragma unroll
        for (int nf = 0; nf < 2; ++nf)
          acc[mf][nf] = MFMA(afr, bfr[nf], acc[mf][nf]);
      }
    }
    __syncthreads();
  }
#pragma unroll
  for (int nf = 0; nf < 2; ++nf) {
    float mn = 3.4e38f;
#pragma unroll
    for (int mf = 0; mf < 10; ++mf)
#pragma unroll
      for (int q = 0; q < 4; ++q) {
        int row = mf * 16 + lhi * 4 + q;
        float e = fn[row] - 2.f * acc[mf][nf][q];
        if (row >= 1 && row <= K_SEL) mn = fminf(mn, e);
      }
    mn = fminf(mn, __shfl_xor(mn, 16, 64));
    mn = fminf(mn, __shfl_xor(mn, 32, 64));
    int p = p0 + wn + nf * 16 + l15;
    if (lhi == 0 && p < P_) {
      float d = fmaxf(mn + pnorm[p], 0.f);
      act_l[(size_t)b * P_ + p] = logf((d + 1.f) / (d + EPS_));
    }
  }
}

// ---------------------------------------------------------------------------
// CLS distances vs proto_global (f32 protos, bf16 cls feature rows).
// ---------------------------------------------------------------------------
__global__ __launch_bounds__(256) void dist_cls(
    const bf16* __restrict__ F, const float* __restrict__ proto,
    const float* __restrict__ fnorm, const float* __restrict__ pnorm,
    float* __restrict__ act_g) {
  int i = blockIdx.x * 256 + threadIdx.x;  // 128*2000 threads exactly
  int b = i / P_, p = i - b * P_;
  const bf16* f = F + (size_t)(b * RPB) * C_;
  const float* pr = proto + (size_t)p * C_;
  float dot = 0.f;
  for (int k = 0; k < C_; k += 8) {
    bf16x8 fv = *reinterpret_cast<const bf16x8*>(f + k);
    float4 p0 = *reinterpret_cast<const float4*>(pr + k);
    float4 p1 = *reinterpret_cast<const float4*>(pr + k + 4);
    dot += (float)fv[0] * p0.x + (float)fv[1] * p0.y + (float)fv[2] * p0.z +
           (float)fv[3] * p0.w + (float)fv[4] * p1.x + (float)fv[5] * p1.y +
           (float)fv[6] * p1.z + (float)fv[7] * p1.w;
  }
  float d = fmaxf(fnorm[b * RPB] - 2.f * dot + pnorm[p], 0.f);
  act_g[i] = logf((d + 1.f) / (d + EPS_));
}

// ---------------------------------------------------------------------------
// final_partial: part[kc][b][c] = sum_{k in chunk} act[b][k] * wT2[c][k]
// final_reduce:  out[b][c] = sum_kc part[kc][b][c]
// ---------------------------------------------------------------------------
__global__ __launch_bounds__(256) void final_partial(
    const float* __restrict__ actg, const float* __restrict__ actl,
    const float* __restrict__ wT2, float* __restrict__ part) {
  __shared__ __align__(16) float sa[KC_][BT_];
  const int kc = blockIdx.x;   // 0..39
  const int bt = blockIdx.y;   // 0..15
  const int t = threadIdx.x;
  const int b0 = bt * BT_;
  const int kg0 = kc * KC_;
  const float* act = (kg0 < 2000) ? actg : actl;
  const int koff = (kg0 < 2000) ? kg0 : kg0 - 2000;
  for (int i = t; i < KC_ * BT_; i += 256) {
    int b = i / KC_;
    int k = i - b * KC_;
    sa[k][b] = act[(size_t)(b0 + b) * P_ + koff + k];
  }
  __syncthreads();
  const int c = t;
  if (c >= NC_) return;
  float acc[BT_] = {};
  const float4* w4p = reinterpret_cast<const float4*>(wT2 + (size_t)c * 4000 + kg0);
#pragma unroll 5
  for (int k4 = 0; k4 < KC_ / 4; ++k4) {
    float4 w4 = w4p[k4];
    float wv[4] = {w4.x, w4.y, w4.z, w4.w};
#pragma unroll
    for (int j = 0; j < 4; ++j) {
      float w = wv[j];
      const float4* s4 = reinterpret_cast<const float4*>(&sa[k4 * 4 + j][0]);
      float4 a0 = s4[0], a1 = s4[1];
      acc[0] += w * a0.x; acc[1] += w * a0.y; acc[2] += w * a0.z; acc[3] += w * a0.w;
      acc[4] += w * a1.x; acc[5] += w * a1.y; acc[6] += w * a1.z; acc[7] += w * a1.w;
    }
  }
#pragma unroll
  for (int b = 0; b < BT_; ++b)
    part[((size_t)kc * B_ + b0 + b) * NC_ + c] = acc[b];
}

__global__ __launch_bounds__(256) void final_reduce(const float* __restrict__ part,
                                                    float* __restrict__ out) {
  int i = blockIdx.x * 256 + threadIdx.x;
  if (i >= B_ * NC_) return;
  float s = 0.f;
#pragma unroll 8
  for (int kc = 0; kc < NKC; ++kc) s += part[(size_t)kc * (B_ * NC_) + i];
  out[i] = s;
}

// ---------------------------------------------------------------------------
extern "C" void kernel_launch(void* const* d_in, const int* in_sizes, int n_in,
                              void* d_out, int out_size, void* d_ws, size_t ws_size,
                              hipStream_t stream) {
  const float* x_tokens = (const float*)d_in[0];
  const float* attn     = (const float*)d_in[1];
  const float* w1 = (const float*)d_in[2];
  const float* b1 = (const float*)d_in[3];
  const float* w2 = (const float*)d_in[4];
  const float* b2 = (const float*)d_in[5];
  const float* w3 = (const float*)d_in[6];
  const float* b3 = (const float*)d_in[7];
  const float* w4 = (const float*)d_in[8];
  const float* b4 = (const float*)d_in[9];
  const float* proto_l = (const float*)d_in[10];
  const float* proto_g = (const float*)d_in[11];
  const float* last_w  = (const float*)d_in[12];
  const float* last_wg = (const float*)d_in[13];
  float* out = (float*)d_out;

  char* wsb = (char*)d_ws;
  auto alloc = [&](size_t bytes) {
    char* p = wsb;
    wsb += (bytes + 255) & ~(size_t)255;
    return p;
  };
  // A0 region (31.5 MB) is dead after gemm1; bufB, wT2, part alias into it.
  bf16* A0   = (bf16*)alloc((size_t)M_PAD * D_IN * sizeof(bf16));   // 31.5 MB
  bf16* bufA = (bf16*)alloc((size_t)M_PAD * 384 * sizeof(bf16));    // 15.7 MB
  bf16* w1b = (bf16*)alloc((size_t)384 * 768 * sizeof(bf16));
  bf16* w2b = (bf16*)alloc((size_t)384 * 384 * sizeof(bf16));
  bf16* w3b = (bf16*)alloc((size_t)192 * 384 * sizeof(bf16));
  bf16* w4b = (bf16*)alloc((size_t)192 * 192 * sizeof(bf16));
  bf16* plb = (bf16*)alloc((size_t)PPAD * C_ * sizeof(bf16));
  int*   rowidx = (int*)  alloc((size_t)M_PAD * sizeof(int));
  float* fnorm  = (float*)alloc((size_t)M_PAD * sizeof(float));
  float* pnl    = (float*)alloc((size_t)PPAD * sizeof(float));
  float* png    = (float*)alloc((size_t)P_ * sizeof(float));
  float* actg   = (float*)alloc((size_t)B_ * P_ * sizeof(float));
  float* actl   = (float*)alloc((size_t)B_ * P_ * sizeof(float));

  // aliases inside A0's 31.5 MB (A0 dead after gemm1; all offsets checked):
  bf16*  bufB = A0;                                        // 15.7 MB used
  float* wT2  = (float*)((char*)A0 + 16 * 1024 * 1024);    // 3.2 MB
  float* part = (float*)((char*)A0 + 20 * 1024 * 1024);    // 4.1 MB (< 31.5)

  bf16* H1 = bufA;   // [M_PAD][384]
  bf16* H2 = bufB;   // [M_PAD][384]  overwrites dead A0
  bf16* H3 = bufA;   // [M_PAD][192]  (H1 dead after gemm2)
  bf16* Fb = bufB;   // [M_PAD][192]  (H2 dead after gemm3; 7.9 MB < 15.7)

  prologue<<<B_ + CVT_TOT / 256, 256, 0, stream>>>(
      attn, rowidx, w1, w2, w3, w4, proto_l, w1b, w2b, w3b, w4b, plb);

  gather_cvt<<<M_PAD, 192, 0, stream>>>(x_tokens, rowidx, A0);

  gemm_bf16<0, 128><<<dim3(M_PAD / 128, 384 / 128), 256, 0, stream>>>(
      A0, w1b, b1, H1, 384, 768);
  gemm_bf16<0, 128><<<dim3(M_PAD / 128, 384 / 128), 256, 0, stream>>>(
      H1, w2b, b2, H2, 384, 384);
  gemm_bf16<0, 64><<<dim3(M_PAD / 128, 192 / 64), 256, 0, stream>>>(
      H2, w3b, b3, H3, 192, 384);
  gemm_bf16<1, 64><<<dim3(M_PAD / 128, 192 / 64), 256, 0, stream>>>(
      H3, w4b, b4, Fb, 192, 192);

  mid_k<<<NORM_BLKS + PREP_BLKS, 256, 0, stream>>>(
      Fb, plb, proto_g, last_wg, last_w, fnorm, pnl, png, wT2);

  dist_img_mfma<<<dim3(PPAD / 128, B_), 256, 0, stream>>>(Fb, plb, fnorm, pnl, actl);
  dist_cls<<<(B_ * P_) / 256, 256, 0, stream>>>(Fb, proto_g, fnorm, png, actg);

  final_partial<<<dim3(NKC, B_ / BT_), 256, 0, stream>>>(actg, actl, wT2, part);
  final_reduce<<<(B_ * NC_ + 255) / 256, 256, 0, stream>>>(part, out);
}

// Round 9
// 148.037 us; speedup vs baseline: 1.2044x; 1.0094x over previous
//
#include <hip/hip_runtime.h>
#include <cstdint>
#include <cstddef>

#define B_     128
#define N_TOK  196
#define D_IN   768
#define K_SEL  144
#define P_     2000
#define PPAD   2048
#define C_     192
#define NC_    200
#define RPB    160            // padded rows per batch: 1 cls + 144 sel + 15 pad
#define M_PAD  (B_ * RPB)     // 20480
#define EPS_   1e-4f
#define KC_    100            // k-chunk for final_partial (4000 = 40*100)
#define NKC    40
#define BT_    8              // batch-tile for final_partial (128 = 16*8)

typedef __bf16 bf16;
typedef bf16 bf16x8 __attribute__((ext_vector_type(8)));
typedef bf16 bf16x4 __attribute__((ext_vector_type(4)));
typedef float f32x4 __attribute__((ext_vector_type(4)));

#define MFMA(a, b, c) __builtin_amdgcn_mfma_f32_16x16x32_bf16(a, b, c, 0, 0, 0)

__device__ __forceinline__ void gload_lds16(const void* g, void* l) {
  __builtin_amdgcn_global_load_lds(
      (const __attribute__((address_space(1))) unsigned int*)g,
      (__attribute__((address_space(3))) unsigned int*)l, 16, 0, 0);
}

// ---------------------------------------------------------------------------
// Prologue: blocks 0..127 = per-batch top-K (stable, lower-index-wins) ->
// rowidx; blocks 128.. = fused f32->bf16 convert of 4 weights + proto_local.
// ---------------------------------------------------------------------------
#define SEG1 73728     // 384*768/4
#define SEG2 36864     // 384*384/4
#define SEG3 18432     // 192*384/4
#define SEG4 9216      // 192*192/4
#define SEG5 98304     // PPAD*C_/4
#define CVT_TOT (SEG1 + SEG2 + SEG3 + SEG4 + SEG5)  // 236544 = 924*256

__global__ __launch_bounds__(256) void prologue(
    const float* __restrict__ attn, int* __restrict__ rowidx,
    const float* __restrict__ w1, const float* __restrict__ w2,
    const float* __restrict__ w3, const float* __restrict__ w4,
    const float* __restrict__ pl,
    bf16* __restrict__ w1b, bf16* __restrict__ w2b,
    bf16* __restrict__ w3b, bf16* __restrict__ w4b,
    bf16* __restrict__ plb) {
  if (blockIdx.x < B_) {
    __shared__ float av[N_TOK];
    __shared__ int   flag[N_TOK];
    int b = blockIdx.x, t = threadIdx.x;
    if (t < N_TOK) av[t] = attn[b * N_TOK + t];
    __syncthreads();
    if (t < N_TOK) {
      float v = av[t];
      int rank = 0;
      for (int j = 0; j < N_TOK; ++j) {
        float u = av[j];
        rank += (u > v || (u == v && j < t)) ? 1 : 0;
      }
      flag[t] = (rank < K_SEL) ? 1 : 0;
    }
    __syncthreads();
    if (t == 0) rowidx[b * RPB] = b * (N_TOK + 1);
    if (t < RPB - (K_SEL + 1)) rowidx[b * RPB + K_SEL + 1 + t] = -1;
    if (t < N_TOK && flag[t]) {
      int pos = 0;
      for (int j = 0; j < t; ++j) pos += flag[j];
      rowidx[b * RPB + 1 + pos] = b * (N_TOK + 1) + 1 + t;
    }
    return;
  }
  int i4 = (blockIdx.x - B_) * 256 + threadIdx.x;
  if (i4 >= CVT_TOT) return;
  const float* s; bf16* d; int nv; int base;
  if (i4 < SEG1)                       { s = w1; d = w1b; nv = 384 * 768; base = i4; }
  else if (i4 < SEG1 + SEG2)           { s = w2; d = w2b; nv = 384 * 384; base = i4 - SEG1; }
  else if (i4 < SEG1 + SEG2 + SEG3)    { s = w3; d = w3b; nv = 192 * 384; base = i4 - (SEG1 + SEG2); }
  else if (i4 < SEG1 + SEG2 + SEG3 + SEG4) { s = w4; d = w4b; nv = 192 * 192; base = i4 - (SEG1 + SEG2 + SEG3); }
  else                                 { s = pl; d = plb; nv = P_ * C_; base = i4 - (SEG1 + SEG2 + SEG3 + SEG4); }
  int i = base * 4;
  bf16x4 o;
#pragma unroll
  for (int j = 0; j < 4; ++j)
    o[j] = (i + j < nv) ? (bf16)s[i + j] : (bf16)0.f;
  *reinterpret_cast<bf16x4*>(d + i) = o;
}

// ---------------------------------------------------------------------------
// Gather selected token rows from x_tokens, convert f32 -> bf16.
// ---------------------------------------------------------------------------
__global__ __launch_bounds__(192) void gather_cvt(const float* __restrict__ x,
                                                  const int* __restrict__ rowidx,
                                                  bf16* __restrict__ A0) {
  int row = blockIdx.x;
  int src = rowidx[row];
  int t = threadIdx.x;
  bf16x4 o;
  if (src >= 0) {
    float4 v = *reinterpret_cast<const float4*>(x + (size_t)src * D_IN + t * 4);
    o[0] = (bf16)v.x; o[1] = (bf16)v.y; o[2] = (bf16)v.z; o[3] = (bf16)v.w;
  } else {
    o[0] = (bf16)0.f; o[1] = (bf16)0.f; o[2] = (bf16)0.f; o[3] = (bf16)0.f;
  }
  *reinterpret_cast<bf16x4*>(A0 + (size_t)row * D_IN + t * 4) = o;
}

// ---------------------------------------------------------------------------
// bf16 MFMA GEMM with 2-phase double-buffered prefetch (T3-minimum):
// stage(t+1) issued BEFORE compute(t); one __syncthreads per K-step.
// BM=128, BN templated, BK=64. 4 waves (2x2), wave tile 64 x (BN/2).
// LDS XOR-swizzled (16B granule) with pre-swizzled global source (rule #21).
// ---------------------------------------------------------------------------
template <int ACT, int BN>
__global__ __launch_bounds__(256, 2) void gemm_bf16(
    const bf16* __restrict__ A, const bf16* __restrict__ W,
    const float* __restrict__ bias, bf16* __restrict__ out, int N, int Kd) {
  constexpr int NF = BN / 32;            // N-frags per wave
  __shared__ __align__(16) bf16 As[2][128 * 64];
  __shared__ __align__(16) bf16 Bs[2][BN * 64];
  const int bm = blockIdx.x * 128, bn = blockIdx.y * BN;
  const int tid = threadIdx.x;
  const int lane = tid & 63, wid = tid >> 6;
  const int wm = (wid >> 1) * 64, wn = (wid & 1) * (BN / 2);
  const int l15 = lane & 15, lhi = lane >> 4;

  auto stage = [&](int buf, int k0) {
#pragma unroll
    for (int i = 0; i < 4; ++i) {
      int o = i * 256 + tid;
      int r = o >> 3, cb = o & 7;
      int gc = (cb ^ (r & 7)) * 8;
      gload_lds16(A + (size_t)(bm + r) * Kd + k0 + gc, (char*)As[buf] + o * 16);
    }
#pragma unroll
    for (int i = 0; i < NF; ++i) {
      int o = i * 256 + tid;
      int r = o >> 3, cb = o & 7;
      int gc = (cb ^ (r & 7)) * 8;
      gload_lds16(W + (size_t)(bn + r) * Kd + k0 + gc, (char*)Bs[buf] + o * 16);
    }
  };

  f32x4 acc[4][NF] = {};
  const int NT = Kd >> 6;
  stage(0, 0);
  __syncthreads();                         // drain stage(0)
  for (int kt = 0; kt < NT; ++kt) {
    if (kt + 1 < NT) stage((kt + 1) & 1, (kt + 1) * 64);
    const char* Ab = (const char*)As[kt & 1];
    const char* Bb = (const char*)Bs[kt & 1];
#pragma unroll
    for (int kk = 0; kk < 2; ++kk) {
      bf16x8 bfr[NF];
#pragma unroll
      for (int nf = 0; nf < NF; ++nf) {
        int rr = wn + nf * 16 + l15;
        int c = kk * 4 + lhi;
        bfr[nf] = *reinterpret_cast<const bf16x8*>(Bb + (rr * 8 + (c ^ (rr & 7))) * 16);
      }
#pragma unroll
      for (int mf = 0; mf < 4; ++mf) {
        int rr = wm + mf * 16 + l15;
        int c = kk * 4 + lhi;
        bf16x8 afr = *reinterpret_cast<const bf16x8*>(Ab + (rr * 8 + (c ^ (rr & 7))) * 16);
#pragma unroll
        for (int nf = 0; nf < NF; ++nf)
          acc[mf][nf] = MFMA(afr, bfr[nf], acc[mf][nf]);
      }
    }
    __syncthreads();                       // drains stage(kt+1); guards reuse
  }
#pragma unroll
  for (int mf = 0; mf < 4; ++mf)
#pragma unroll
    for (int nf = 0; nf < NF; ++nf) {
      int col = bn + wn + nf * 16 + l15;
      float bv = bias[col];
#pragma unroll
      for (int q = 0; q < 4; ++q) {
        int row = bm + wm + mf * 16 + lhi * 4 + q;
        float v = acc[mf][nf][q] + bv;
        v = (ACT == 0) ? fmaxf(v, 0.f) : 1.f / (1.f + expf(-v));
        out[(size_t)row * N + col] = (bf16)v;
      }
    }
}

// ---------------------------------------------------------------------------
// Mid kernel: blocks [0, NORM_BLKS) = norms; rest = prep_wt (wT2[c][k]).
// ---------------------------------------------------------------------------
#define NORM_BLKS ((M_PAD + PPAD + P_) / 4)          // 6132
#define PREP_Q    (NC_ * 4000 / 4)                   // 200000 float4s
#define PREP_BLKS ((PREP_Q + 255) / 256)             // 782

__global__ __launch_bounds__(256) void mid_k(
    const bf16* __restrict__ F, const bf16* __restrict__ plb,
    const float* __restrict__ pg, const float* __restrict__ lwg,
    const float* __restrict__ lw, float* __restrict__ fnorm,
    float* __restrict__ pnl, float* __restrict__ png,
    float* __restrict__ wT2) {
  if (blockIdx.x < NORM_BLKS) {
    int m = blockIdx.x * 4 + (threadIdx.x >> 6);
    int lane = threadIdx.x & 63;
    float s = 0.f;
    if (m < M_PAD) {
      const bf16* f = F + (size_t)m * C_;
#pragma unroll
      for (int k = 0; k < 3; ++k) { float v = (float)f[lane + k * 64]; s += v * v; }
    } else if (m < M_PAD + PPAD) {
      const bf16* f = plb + (size_t)(m - M_PAD) * C_;
#pragma unroll
      for (int k = 0; k < 3; ++k) { float v = (float)f[lane + k * 64]; s += v * v; }
    } else {
      const float* f = pg + (size_t)(m - M_PAD - PPAD) * C_;
#pragma unroll
      for (int k = 0; k < 3; ++k) { float v = f[lane + k * 64]; s += v * v; }
    }
    for (int o = 32; o > 0; o >>= 1) s += __shfl_down(s, o, 64);
    if (lane == 0) {
      if (m < M_PAD) fnorm[m] = s;
      else if (m < M_PAD + PPAD) pnl[m - M_PAD] = s;
      else png[m - M_PAD - PPAD] = s;
    }
    return;
  }
  int i4 = (blockIdx.x - NORM_BLKS) * 256 + threadIdx.x;
  if (i4 >= PREP_Q) return;
  int c = i4 / 1000, k4 = i4 - c * 1000;   // 1000 float4s per c-row
  float4 v;
  if (k4 < 500) {
    v = *reinterpret_cast<const float4*>(lwg + (size_t)c * 2000 + k4 * 4);
    v.x *= 0.3f; v.y *= 0.3f; v.z *= 0.3f; v.w *= 0.3f;
  } else {
    v = *reinterpret_cast<const float4*>(lw + (size_t)c * 2000 + (k4 - 500) * 4);
    v.x *= 0.7f; v.y *= 0.7f; v.z *= 0.7f; v.w *= 0.7f;
  }
  *reinterpret_cast<float4*>(wT2 + (size_t)i4 * 4) = v;
}

// ---------------------------------------------------------------------------
// Fused distances, one dispatch:
// blocks [0, 2048):  per-(proto-tile, batch) image distances, 2-phase dbuf
//                    MFMA + min-over-tokens + log activation.
// blocks [2048, 3048): cls distances vs proto_global (1 thread per (b,p)).
// ---------------------------------------------------------------------------
#define NIMG_BLKS (PPAD / 128 * B_)     // 2048
#define NCLS_BLKS (B_ * P_ / 256)       // 1000

__global__ __launch_bounds__(256, 2) void dist_fused(
    const bf16* __restrict__ F, const bf16* __restrict__ P,
    const float* __restrict__ fnorm, const float* __restrict__ pnl,
    const float* __restrict__ proto_g, const float* __restrict__ png,
    float* __restrict__ act_l, float* __restrict__ act_g) {
  __shared__ __align__(16) bf16 Fs[2][160 * 64];
  __shared__ __align__(16) bf16 Ps[2][128 * 64];
  __shared__ float fn[RPB];
  const int tid = threadIdx.x;
  if (blockIdx.x >= NIMG_BLKS) {
    // ---- cls-distance branch
    int i = (blockIdx.x - NIMG_BLKS) * 256 + tid;  // < 128*2000 exactly
    int b = i / P_, p = i - b * P_;
    const bf16* f = F + (size_t)(b * RPB) * C_;
    const float* pr = proto_g + (size_t)p * C_;
    float dot = 0.f;
    for (int k = 0; k < C_; k += 8) {
      bf16x8 fv = *reinterpret_cast<const bf16x8*>(f + k);
      float4 p0 = *reinterpret_cast<const float4*>(pr + k);
      float4 p1 = *reinterpret_cast<const float4*>(pr + k + 4);
      dot += (float)fv[0] * p0.x + (float)fv[1] * p0.y + (float)fv[2] * p0.z +
             (float)fv[3] * p0.w + (float)fv[4] * p1.x + (float)fv[5] * p1.y +
             (float)fv[6] * p1.z + (float)fv[7] * p1.w;
    }
    float d = fmaxf(fnorm[b * RPB] - 2.f * dot + png[p], 0.f);
    act_g[i] = logf((d + 1.f) / (d + EPS_));
    return;
  }
  // ---- image-distance branch (2-phase double-buffered)
  const int b = blockIdx.x >> 4;
  const int p0 = (blockIdx.x & 15) * 128;
  const int lane = tid & 63, wid = tid >> 6;
  const int wn = wid * 32;
  const int l15 = lane & 15, lhi = lane >> 4;

  auto stage = [&](int buf, int k0) {
#pragma unroll
    for (int i = 0; i < 5; ++i) {
      int o = i * 256 + tid;
      int r = o >> 3, cb = o & 7;
      int gc = (cb ^ (r & 7)) * 8;
      gload_lds16(F + (size_t)(b * RPB + r) * C_ + k0 + gc, (char*)Fs[buf] + o * 16);
    }
#pragma unroll
    for (int i = 0; i < 4; ++i) {
      int o = i * 256 + tid;
      int r = o >> 3, cb = o & 7;
      int gc = (cb ^ (r & 7)) * 8;
      gload_lds16(P + (size_t)(p0 + r) * C_ + k0 + gc, (char*)Ps[buf] + o * 16);
    }
  };

  if (tid < RPB) fn[tid] = fnorm[b * RPB + tid];
  f32x4 acc[10][2] = {};
  stage(0, 0);
  __syncthreads();
  for (int kt = 0; kt < 3; ++kt) {
    if (kt + 1 < 3) stage((kt + 1) & 1, (kt + 1) * 64);
    const char* Fbuf = (const char*)Fs[kt & 1];
    const char* Pbuf = (const char*)Ps[kt & 1];
#pragma unroll
    for (int kk = 0; kk < 2; ++kk) {
      bf16x8 bfr[2];
#pragma unroll
      for (int nf = 0; nf < 2; ++nf) {
        int rr = wn + nf * 16 + l15;
        int c = kk * 4 + lhi;
        bfr[nf] = *reinterpret_cast<const bf16x8*>(Pbuf + (rr * 8 + (c ^ (rr & 7))) * 16);
      }
#pragma unroll
      for (int mf = 0; mf < 10; ++mf) {
        int rr = mf * 16 + l15;
        int c = kk * 4 + lhi;
        bf16x8 afr = *reinterpret_cast<const bf16x8*>(Fbuf + (rr * 8 + (c ^ (rr & 7))) * 16);
#pragma unroll
        for (int nf = 0; nf < 2; ++nf)
          acc[mf][nf] = MFMA(afr, bfr[nf], acc[mf][nf]);
      }
    }
    __syncthreads();
  }
#pragma unroll
  for (int nf = 0; nf < 2; ++nf) {
    float mn = 3.4e38f;
#pragma unroll
    for (int mf = 0; mf < 10; ++mf)
#pragma unroll
      for (int q = 0; q < 4; ++q) {
        int row = mf * 16 + lhi * 4 + q;
        float e = fn[row] - 2.f * acc[mf][nf][q];
        if (row >= 1 && row <= K_SEL) mn = fminf(mn, e);
      }
    mn = fminf(mn, __shfl_xor(mn, 16, 64));
    mn = fminf(mn, __shfl_xor(mn, 32, 64));
    int p = p0 + wn + nf * 16 + l15;
    if (lhi == 0 && p < P_) {
      float d = fmaxf(mn + pnl[p], 0.f);
      act_l[(size_t)b * P_ + p] = logf((d + 1.f) / (d + EPS_));
    }
  }
}

// ---------------------------------------------------------------------------
// final_partial: part[kc][b][c] = sum_{k in chunk} act[b][k] * wT2[c][k]
// final_reduce:  out[b][c] = sum_kc part[kc][b][c]
// ---------------------------------------------------------------------------
__global__ __launch_bounds__(256) void final_partial(
    const float* __restrict__ actg, const float* __restrict__ actl,
    const float* __restrict__ wT2, float* __restrict__ part) {
  __shared__ __align__(16) float sa[KC_][BT_];
  const int kc = blockIdx.x;   // 0..39
  const int bt = blockIdx.y;   // 0..15
  const int t = threadIdx.x;
  const int b0 = bt * BT_;
  const int kg0 = kc * KC_;
  const float* act = (kg0 < 2000) ? actg : actl;
  const int koff = (kg0 < 2000) ? kg0 : kg0 - 2000;
  for (int i = t; i < KC_ * BT_; i += 256) {
    int b = i / KC_;
    int k = i - b * KC_;
    sa[k][b] = act[(size_t)(b0 + b) * P_ + koff + k];
  }
  __syncthreads();
  const int c = t;
  if (c >= NC_) return;
  float acc[BT_] = {};
  const float4* w4p = reinterpret_cast<const float4*>(wT2 + (size_t)c * 4000 + kg0);
#pragma unroll 5
  for (int k4 = 0; k4 < KC_ / 4; ++k4) {
    float4 w4 = w4p[k4];
    float wv[4] = {w4.x, w4.y, w4.z, w4.w};
#pragma unroll
    for (int j = 0; j < 4; ++j) {
      float w = wv[j];
      const float4* s4 = reinterpret_cast<const float4*>(&sa[k4 * 4 + j][0]);
      float4 a0 = s4[0], a1 = s4[1];
      acc[0] += w * a0.x; acc[1] += w * a0.y; acc[2] += w * a0.z; acc[3] += w * a0.w;
      acc[4] += w * a1.x; acc[5] += w * a1.y; acc[6] += w * a1.z; acc[7] += w * a1.w;
    }
  }
#pragma unroll
  for (int b = 0; b < BT_; ++b)
    part[((size_t)kc * B_ + b0 + b) * NC_ + c] = acc[b];
}

__global__ __launch_bounds__(256) void final_reduce(const float* __restrict__ part,
                                                    float* __restrict__ out) {
  int i = blockIdx.x * 256 + threadIdx.x;
  if (i >= B_ * NC_) return;
  float s = 0.f;
#pragma unroll 8
  for (int kc = 0; kc < NKC; ++kc) s += part[(size_t)kc * (B_ * NC_) + i];
  out[i] = s;
}

// ---------------------------------------------------------------------------
extern "C" void kernel_launch(void* const* d_in, const int* in_sizes, int n_in,
                              void* d_out, int out_size, void* d_ws, size_t ws_size,
                              hipStream_t stream) {
  const float* x_tokens = (const float*)d_in[0];
  const float* attn     = (const float*)d_in[1];
  const float* w1 = (const float*)d_in[2];
  const float* b1 = (const float*)d_in[3];
  const float* w2 = (const float*)d_in[4];
  const float* b2 = (const float*)d_in[5];
  const float* w3 = (const float*)d_in[6];
  const float* b3 = (const float*)d_in[7];
  const float* w4 = (const float*)d_in[8];
  const float* b4 = (const float*)d_in[9];
  const float* proto_l = (const float*)d_in[10];
  const float* proto_g = (const float*)d_in[11];
  const float* last_w  = (const float*)d_in[12];
  const float* last_wg = (const float*)d_in[13];
  float* out = (float*)d_out;

  char* wsb = (char*)d_ws;
  auto alloc = [&](size_t bytes) {
    char* p = wsb;
    wsb += (bytes + 255) & ~(size_t)255;
    return p;
  };
  // A0 region (31.5 MB) is dead after gemm1; bufB, wT2, part alias into it.
  bf16* A0   = (bf16*)alloc((size_t)M_PAD * D_IN * sizeof(bf16));   // 31.5 MB
  bf16* bufA = (bf16*)alloc((size_t)M_PAD * 384 * sizeof(bf16));    // 15.7 MB
  bf16* w1b = (bf16*)alloc((size_t)384 * 768 * sizeof(bf16));
  bf16* w2b = (bf16*)alloc((size_t)384 * 384 * sizeof(bf16));
  bf16* w3b = (bf16*)alloc((size_t)192 * 384 * sizeof(bf16));
  bf16* w4b = (bf16*)alloc((size_t)192 * 192 * sizeof(bf16));
  bf16* plb = (bf16*)alloc((size_t)PPAD * C_ * sizeof(bf16));
  int*   rowidx = (int*)  alloc((size_t)M_PAD * sizeof(int));
  float* fnorm  = (float*)alloc((size_t)M_PAD * sizeof(float));
  float* pnl    = (float*)alloc((size_t)PPAD * sizeof(float));
  float* png    = (float*)alloc((size_t)P_ * sizeof(float));
  float* actg   = (float*)alloc((size_t)B_ * P_ * sizeof(float));
  float* actl   = (float*)alloc((size_t)B_ * P_ * sizeof(float));

  // aliases inside A0's 31.5 MB (A0 dead after gemm1; all offsets checked):
  bf16*  bufB = A0;                                        // 15.7 MB used
  float* wT2  = (float*)((char*)A0 + 16 * 1024 * 1024);    // 3.2 MB
  float* part = (float*)((char*)A0 + 20 * 1024 * 1024);    // 4.1 MB (< 31.5)

  bf16* H1 = bufA;   // [M_PAD][384]
  bf16* H2 = bufB;   // [M_PAD][384]  overwrites dead A0
  bf16* H3 = bufA;   // [M_PAD][192]  (H1 dead after gemm2)
  bf16* Fb = bufB;   // [M_PAD][192]  (H2 dead after gemm3; 7.9 MB < 15.7)

  prologue<<<B_ + CVT_TOT / 256, 256, 0, stream>>>(
      attn, rowidx, w1, w2, w3, w4, proto_l, w1b, w2b, w3b, w4b, plb);

  gather_cvt<<<M_PAD, 192, 0, stream>>>(x_tokens, rowidx, A0);

  gemm_bf16<0, 128><<<dim3(M_PAD / 128, 384 / 128), 256, 0, stream>>>(
      A0, w1b, b1, H1, 384, 768);
  gemm_bf16<0, 128><<<dim3(M_PAD / 128, 384 / 128), 256, 0, stream>>>(
      H1, w2b, b2, H2, 384, 384);
  gemm_bf16<0, 64><<<dim3(M_PAD / 128, 192 / 64), 256, 0, stream>>>(
      H2, w3b, b3, H3, 192, 384);
  gemm_bf16<1, 64><<<dim3(M_PAD / 128, 192 / 64), 256, 0, stream>>>(
      H3, w4b, b4, Fb, 192, 192);

  mid_k<<<NORM_BLKS + PREP_BLKS, 256, 0, stream>>>(
      Fb, plb, proto_g, last_wg, last_w, fnorm, pnl, png, wT2);

  dist_fused<<<NIMG_BLKS + NCLS_BLKS, 256, 0, stream>>>(
      Fb, plb, fnorm, pnl, proto_g, png, actl, actg);

  final_partial<<<dim3(NKC, B_ / BT_), 256, 0, stream>>>(actg, actl, wT2, part);
  final_reduce<<<(B_ * NC_ + 255) / 256, 256, 0, stream>>>(part, out);
}

// Round 10
// 144.907 us; speedup vs baseline: 1.2304x; 1.0216x over previous
//
#include <hip/hip_runtime.h>
#include <cstdint>
#include <cstddef>

#define B_     128
#define N_TOK  196
#define D_IN   768
#define K_SEL  144
#define P_     2000
#define PPAD   2048
#define C_     192
#define NC_    200
#define RPB    160            // padded rows per batch: 1 cls + 144 sel + 15 pad
#define M_PAD  (B_ * RPB)     // 20480
#define EPS_   1e-4f
#define KC_    100            // k-chunk for final_partial (4000 = 40*100)
#define NKC    40
#define BT_    8              // batch-tile for final_partial (128 = 16*8)

typedef __bf16 bf16;
typedef bf16 bf16x8 __attribute__((ext_vector_type(8)));
typedef bf16 bf16x4 __attribute__((ext_vector_type(4)));
typedef float f32x4 __attribute__((ext_vector_type(4)));

#define MFMA(a, b, c) __builtin_amdgcn_mfma_f32_16x16x32_bf16(a, b, c, 0, 0, 0)

__device__ __forceinline__ void gload_lds16(const void* g, void* l) {
  __builtin_amdgcn_global_load_lds(
      (const __attribute__((address_space(1))) unsigned int*)g,
      (__attribute__((address_space(3))) unsigned int*)l, 16, 0, 0);
}

// ---------------------------------------------------------------------------
// Prologue: blocks 0..127 = per-batch top-K (stable, lower-index-wins) ->
// rowidx; blocks 128.. = fused f32->bf16 convert of 4 weights + proto_local.
// ---------------------------------------------------------------------------
#define SEG1 73728     // 384*768/4
#define SEG2 36864     // 384*384/4
#define SEG3 18432     // 192*384/4
#define SEG4 9216      // 192*192/4
#define SEG5 98304     // PPAD*C_/4
#define CVT_TOT (SEG1 + SEG2 + SEG3 + SEG4 + SEG5)  // 236544 = 924*256

__global__ __launch_bounds__(256) void prologue(
    const float* __restrict__ attn, int* __restrict__ rowidx,
    const float* __restrict__ w1, const float* __restrict__ w2,
    const float* __restrict__ w3, const float* __restrict__ w4,
    const float* __restrict__ pl,
    bf16* __restrict__ w1b, bf16* __restrict__ w2b,
    bf16* __restrict__ w3b, bf16* __restrict__ w4b,
    bf16* __restrict__ plb) {
  if (blockIdx.x < B_) {
    __shared__ float av[N_TOK];
    __shared__ int   flag[N_TOK];
    int b = blockIdx.x, t = threadIdx.x;
    if (t < N_TOK) av[t] = attn[b * N_TOK + t];
    __syncthreads();
    if (t < N_TOK) {
      float v = av[t];
      int rank = 0;
      for (int j = 0; j < N_TOK; ++j) {
        float u = av[j];
        rank += (u > v || (u == v && j < t)) ? 1 : 0;
      }
      flag[t] = (rank < K_SEL) ? 1 : 0;
    }
    __syncthreads();
    if (t == 0) rowidx[b * RPB] = b * (N_TOK + 1);
    if (t < RPB - (K_SEL + 1)) rowidx[b * RPB + K_SEL + 1 + t] = -1;
    if (t < N_TOK && flag[t]) {
      int pos = 0;
      for (int j = 0; j < t; ++j) pos += flag[j];
      rowidx[b * RPB + 1 + pos] = b * (N_TOK + 1) + 1 + t;
    }
    return;
  }
  int i4 = (blockIdx.x - B_) * 256 + threadIdx.x;
  if (i4 >= CVT_TOT) return;
  const float* s; bf16* d; int nv; int base;
  if (i4 < SEG1)                       { s = w1; d = w1b; nv = 384 * 768; base = i4; }
  else if (i4 < SEG1 + SEG2)           { s = w2; d = w2b; nv = 384 * 384; base = i4 - SEG1; }
  else if (i4 < SEG1 + SEG2 + SEG3)    { s = w3; d = w3b; nv = 192 * 384; base = i4 - (SEG1 + SEG2); }
  else if (i4 < SEG1 + SEG2 + SEG3 + SEG4) { s = w4; d = w4b; nv = 192 * 192; base = i4 - (SEG1 + SEG2 + SEG3); }
  else                                 { s = pl; d = plb; nv = P_ * C_; base = i4 - (SEG1 + SEG2 + SEG3 + SEG4); }
  int i = base * 4;
  bf16x4 o;
#pragma unroll
  for (int j = 0; j < 4; ++j)
    o[j] = (i + j < nv) ? (bf16)s[i + j] : (bf16)0.f;
  *reinterpret_cast<bf16x4*>(d + i) = o;
}

// ---------------------------------------------------------------------------
// Gather selected token rows from x_tokens, convert f32 -> bf16.
// ---------------------------------------------------------------------------
__global__ __launch_bounds__(192) void gather_cvt(const float* __restrict__ x,
                                                  const int* __restrict__ rowidx,
                                                  bf16* __restrict__ A0) {
  int row = blockIdx.x;
  int src = rowidx[row];
  int t = threadIdx.x;
  bf16x4 o;
  if (src >= 0) {
    float4 v = *reinterpret_cast<const float4*>(x + (size_t)src * D_IN + t * 4);
    o[0] = (bf16)v.x; o[1] = (bf16)v.y; o[2] = (bf16)v.z; o[3] = (bf16)v.w;
  } else {
    o[0] = (bf16)0.f; o[1] = (bf16)0.f; o[2] = (bf16)0.f; o[3] = (bf16)0.f;
  }
  *reinterpret_cast<bf16x4*>(A0 + (size_t)row * D_IN + t * 4) = o;
}

// ---------------------------------------------------------------------------
// bf16 MFMA GEMM with 2-phase double-buffered prefetch (T3-minimum):
// stage(t+1) issued BEFORE compute(t); one __syncthreads per K-step.
// BM=128, BN templated, BK=64. 4 waves (2x2), wave tile 64 x (BN/2).
// LDS XOR-swizzled (16B granule) with pre-swizzled global source (rule #21).
// ---------------------------------------------------------------------------
template <int ACT, int BN>
__global__ __launch_bounds__(256, 2) void gemm_bf16(
    const bf16* __restrict__ A, const bf16* __restrict__ W,
    const float* __restrict__ bias, bf16* __restrict__ out, int N, int Kd) {
  constexpr int NF = BN / 32;            // N-frags per wave
  __shared__ __align__(16) bf16 As[2][128 * 64];
  __shared__ __align__(16) bf16 Bs[2][BN * 64];
  const int bm = blockIdx.x * 128, bn = blockIdx.y * BN;
  const int tid = threadIdx.x;
  const int lane = tid & 63, wid = tid >> 6;
  const int wm = (wid >> 1) * 64, wn = (wid & 1) * (BN / 2);
  const int l15 = lane & 15, lhi = lane >> 4;

  auto stage = [&](int buf, int k0) {
#pragma unroll
    for (int i = 0; i < 4; ++i) {
      int o = i * 256 + tid;
      int r = o >> 3, cb = o & 7;
      int gc = (cb ^ (r & 7)) * 8;
      gload_lds16(A + (size_t)(bm + r) * Kd + k0 + gc, (char*)As[buf] + o * 16);
    }
#pragma unroll
    for (int i = 0; i < NF; ++i) {
      int o = i * 256 + tid;
      int r = o >> 3, cb = o & 7;
      int gc = (cb ^ (r & 7)) * 8;
      gload_lds16(W + (size_t)(bn + r) * Kd + k0 + gc, (char*)Bs[buf] + o * 16);
    }
  };

  f32x4 acc[4][NF] = {};
  const int NT = Kd >> 6;
  stage(0, 0);
  __syncthreads();                         // drain stage(0)
  for (int kt = 0; kt < NT; ++kt) {
    if (kt + 1 < NT) stage((kt + 1) & 1, (kt + 1) * 64);
    const char* Ab = (const char*)As[kt & 1];
    const char* Bb = (const char*)Bs[kt & 1];
#pragma unroll
    for (int kk = 0; kk < 2; ++kk) {
      bf16x8 bfr[NF];
#pragma unroll
      for (int nf = 0; nf < NF; ++nf) {
        int rr = wn + nf * 16 + l15;
        int c = kk * 4 + lhi;
        bfr[nf] = *reinterpret_cast<const bf16x8*>(Bb + (rr * 8 + (c ^ (rr & 7))) * 16);
      }
#pragma unroll
      for (int mf = 0; mf < 4; ++mf) {
        int rr = wm + mf * 16 + l15;
        int c = kk * 4 + lhi;
        bf16x8 afr = *reinterpret_cast<const bf16x8*>(Ab + (rr * 8 + (c ^ (rr & 7))) * 16);
#pragma unroll
        for (int nf = 0; nf < NF; ++nf)
          acc[mf][nf] = MFMA(afr, bfr[nf], acc[mf][nf]);
      }
    }
    __syncthreads();                       // drains stage(kt+1); guards reuse
  }
#pragma unroll
  for (int mf = 0; mf < 4; ++mf)
#pragma unroll
    for (int nf = 0; nf < NF; ++nf) {
      int col = bn + wn + nf * 16 + l15;
      float bv = bias[col];
#pragma unroll
      for (int q = 0; q < 4; ++q) {
        int row = bm + wm + mf * 16 + lhi * 4 + q;
        float v = acc[mf][nf][q] + bv;
        v = (ACT == 0) ? fmaxf(v, 0.f) : 1.f / (1.f + expf(-v));
        out[(size_t)row * N + col] = (bf16)v;
      }
    }
}

// ---------------------------------------------------------------------------
// Mid kernel: blocks [0, NORM_BLKS) = norms; rest = prep_wt (wT2[c][k]).
// ---------------------------------------------------------------------------
#define NORM_BLKS ((M_PAD + PPAD + P_) / 4)          // 6132
#define PREP_Q    (NC_ * 4000 / 4)                   // 200000 float4s
#define PREP_BLKS ((PREP_Q + 255) / 256)             // 782

__global__ __launch_bounds__(256) void mid_k(
    const bf16* __restrict__ F, const bf16* __restrict__ plb,
    const float* __restrict__ pg, const float* __restrict__ lwg,
    const float* __restrict__ lw, float* __restrict__ fnorm,
    float* __restrict__ pnl, float* __restrict__ png,
    float* __restrict__ wT2) {
  if (blockIdx.x < NORM_BLKS) {
    int m = blockIdx.x * 4 + (threadIdx.x >> 6);
    int lane = threadIdx.x & 63;
    float s = 0.f;
    if (m < M_PAD) {
      const bf16* f = F + (size_t)m * C_;
#pragma unroll
      for (int k = 0; k < 3; ++k) { float v = (float)f[lane + k * 64]; s += v * v; }
    } else if (m < M_PAD + PPAD) {
      const bf16* f = plb + (size_t)(m - M_PAD) * C_;
#pragma unroll
      for (int k = 0; k < 3; ++k) { float v = (float)f[lane + k * 64]; s += v * v; }
    } else {
      const float* f = pg + (size_t)(m - M_PAD - PPAD) * C_;
#pragma unroll
      for (int k = 0; k < 3; ++k) { float v = f[lane + k * 64]; s += v * v; }
    }
    for (int o = 32; o > 0; o >>= 1) s += __shfl_down(s, o, 64);
    if (lane == 0) {
      if (m < M_PAD) fnorm[m] = s;
      else if (m < M_PAD + PPAD) pnl[m - M_PAD] = s;
      else png[m - M_PAD - PPAD] = s;
    }
    return;
  }
  int i4 = (blockIdx.x - NORM_BLKS) * 256 + threadIdx.x;
  if (i4 >= PREP_Q) return;
  int c = i4 / 1000, k4 = i4 - c * 1000;   // 1000 float4s per c-row
  float4 v;
  if (k4 < 500) {
    v = *reinterpret_cast<const float4*>(lwg + (size_t)c * 2000 + k4 * 4);
    v.x *= 0.3f; v.y *= 0.3f; v.z *= 0.3f; v.w *= 0.3f;
  } else {
    v = *reinterpret_cast<const float4*>(lw + (size_t)c * 2000 + (k4 - 500) * 4);
    v.x *= 0.7f; v.y *= 0.7f; v.z *= 0.7f; v.w *= 0.7f;
  }
  *reinterpret_cast<float4*>(wT2 + (size_t)i4 * 4) = v;
}

// ---------------------------------------------------------------------------
// Fused distances, one dispatch:
// blocks [0, 2048):  image distances, 144 token rows (9 m-frags), 2-phase
//                    dbuf MFMA + min-over-tokens + log act. XCD-chunked
//                    swizzle: logical = (phys%8)*256 + phys/8, so all 16
//                    proto-tiles of a batch group share one XCD's L2.
// blocks [2048, 3048): cls distances vs proto_global (1 thread per (b,p)).
// ---------------------------------------------------------------------------
#define NIMG_BLKS (PPAD / 128 * B_)     // 2048
#define NCLS_BLKS (B_ * P_ / 256)       // 1000
#define FG_ (K_SEL * 8)                 // 1152 F granules per K-step

__global__ __launch_bounds__(256, 2) void dist_fused(
    const bf16* __restrict__ F, const bf16* __restrict__ P,
    const float* __restrict__ fnorm, const float* __restrict__ pnl,
    const float* __restrict__ proto_g, const float* __restrict__ png,
    float* __restrict__ act_l, float* __restrict__ act_g) {
  __shared__ __align__(16) bf16 Fs[2][K_SEL * 64];
  __shared__ __align__(16) bf16 Ps[2][128 * 64];
  __shared__ float fn[K_SEL];
  const int tid = threadIdx.x;
  if (blockIdx.x >= NIMG_BLKS) {
    // ---- cls-distance branch
    int i = (blockIdx.x - NIMG_BLKS) * 256 + tid;  // < 128*2000 exactly
    int b = i / P_, p = i - b * P_;
    const bf16* f = F + (size_t)(b * RPB) * C_;
    const float* pr = proto_g + (size_t)p * C_;
    float dot = 0.f;
    for (int k = 0; k < C_; k += 8) {
      bf16x8 fv = *reinterpret_cast<const bf16x8*>(f + k);
      float4 p0 = *reinterpret_cast<const float4*>(pr + k);
      float4 p1 = *reinterpret_cast<const float4*>(pr + k + 4);
      dot += (float)fv[0] * p0.x + (float)fv[1] * p0.y + (float)fv[2] * p0.z +
             (float)fv[3] * p0.w + (float)fv[4] * p1.x + (float)fv[5] * p1.y +
             (float)fv[6] * p1.z + (float)fv[7] * p1.w;
    }
    float d = fmaxf(fnorm[b * RPB] - 2.f * dot + png[p], 0.f);
    act_g[i] = logf((d + 1.f) / (d + EPS_));
    return;
  }
  // ---- image-distance branch (2-phase dbuf, 144 rows, XCD-chunk swizzle)
  const int lb = (blockIdx.x & 7) * (NIMG_BLKS / 8) + (blockIdx.x >> 3);
  const int b = lb >> 4;
  const int p0 = (lb & 15) * 128;
  const int lane = tid & 63, wid = tid >> 6;
  const int wn = wid * 32;
  const int l15 = lane & 15, lhi = lane >> 4;
  const bf16* Fbase = F + (size_t)(b * RPB + 1) * C_;   // selected rows only

  auto stage = [&](int buf, int k0) {
#pragma unroll
    for (int i = 0; i < 5; ++i) {
      int o = i * 256 + tid;
      if (o < FG_) {
        int r = o >> 3, cb = o & 7;
        int gc = (cb ^ (r & 7)) * 8;
        gload_lds16(Fbase + (size_t)r * C_ + k0 + gc, (char*)Fs[buf] + o * 16);
      }
    }
#pragma unroll
    for (int i = 0; i < 4; ++i) {
      int o = i * 256 + tid;
      int r = o >> 3, cb = o & 7;
      int gc = (cb ^ (r & 7)) * 8;
      gload_lds16(P + (size_t)(p0 + r) * C_ + k0 + gc, (char*)Ps[buf] + o * 16);
    }
  };

  if (tid < K_SEL) fn[tid] = fnorm[b * RPB + 1 + tid];
  f32x4 acc[9][2] = {};
  stage(0, 0);
  __syncthreads();
  for (int kt = 0; kt < 3; ++kt) {
    if (kt + 1 < 3) stage((kt + 1) & 1, (kt + 1) * 64);
    const char* Fbuf = (const char*)Fs[kt & 1];
    const char* Pbuf = (const char*)Ps[kt & 1];
#pragma unroll
    for (int kk = 0; kk < 2; ++kk) {
      bf16x8 bfr[2];
#pragma unroll
      for (int nf = 0; nf < 2; ++nf) {
        int rr = wn + nf * 16 + l15;
        int c = kk * 4 + lhi;
        bfr[nf] = *reinterpret_cast<const bf16x8*>(Pbuf + (rr * 8 + (c ^ (rr & 7))) * 16);
      }
#pragma unroll
      for (int mf = 0; mf < 9; ++mf) {
        int rr = mf * 16 + l15;
        int c = kk * 4 + lhi;
        bf16x8 afr = *reinterpret_cast<const bf16x8*>(Fbuf + (rr * 8 + (c ^ (rr & 7))) * 16);
#pragma unroll
        for (int nf = 0; nf < 2; ++nf)
          acc[mf][nf] = MFMA(afr, bfr[nf], acc[mf][nf]);
      }
    }
    __syncthreads();
  }
#pragma unroll
  for (int nf = 0; nf < 2; ++nf) {
    float mn = 3.4e38f;
#pragma unroll
    for (int mf = 0; mf < 9; ++mf)
#pragma unroll
      for (int q = 0; q < 4; ++q) {
        int row = mf * 16 + lhi * 4 + q;
        mn = fminf(mn, fn[row] - 2.f * acc[mf][nf][q]);
      }
    mn = fminf(mn, __shfl_xor(mn, 16, 64));
    mn = fminf(mn, __shfl_xor(mn, 32, 64));
    int p = p0 + wn + nf * 16 + l15;
    if (lhi == 0 && p < P_) {
      float d = fmaxf(mn + pnl[p], 0.f);
      act_l[(size_t)b * P_ + p] = logf((d + 1.f) / (d + EPS_));
    }
  }
}

// ---------------------------------------------------------------------------
// final_partial: part[kc][b][c] = sum_{k in chunk} act[b][k] * wT2[c][k]
// final_reduce:  out[b][c] = sum_kc part[kc][b][c]
// ---------------------------------------------------------------------------
__global__ __launch_bounds__(256) void final_partial(
    const float* __restrict__ actg, const float* __restrict__ actl,
    const float* __restrict__ wT2, float* __restrict__ part) {
  __shared__ __align__(16) float sa[KC_][BT_];
  const int kc = blockIdx.x;   // 0..39
  const int bt = blockIdx.y;   // 0..15
  const int t = threadIdx.x;
  const int b0 = bt * BT_;
  const int kg0 = kc * KC_;
  const float* act = (kg0 < 2000) ? actg : actl;
  const int koff = (kg0 < 2000) ? kg0 : kg0 - 2000;
  for (int i = t; i < KC_ * BT_; i += 256) {
    int b = i / KC_;
    int k = i - b * KC_;
    sa[k][b] = act[(size_t)(b0 + b) * P_ + koff + k];
  }
  __syncthreads();
  const int c = t;
  if (c >= NC_) return;
  float acc[BT_] = {};
  const float4* w4p = reinterpret_cast<const float4*>(wT2 + (size_t)c * 4000 + kg0);
#pragma unroll 5
  for (int k4 = 0; k4 < KC_ / 4; ++k4) {
    float4 w4 = w4p[k4];
    float wv[4] = {w4.x, w4.y, w4.z, w4.w};
#pragma unroll
    for (int j = 0; j < 4; ++j) {
      float w = wv[j];
      const float4* s4 = reinterpret_cast<const float4*>(&sa[k4 * 4 + j][0]);
      float4 a0 = s4[0], a1 = s4[1];
      acc[0] += w * a0.x; acc[1] += w * a0.y; acc[2] += w * a0.z; acc[3] += w * a0.w;
      acc[4] += w * a1.x; acc[5] += w * a1.y; acc[6] += w * a1.z; acc[7] += w * a1.w;
    }
  }
#pragma unroll
  for (int b = 0; b < BT_; ++b)
    part[((size_t)kc * B_ + b0 + b) * NC_ + c] = acc[b];
}

__global__ __launch_bounds__(256) void final_reduce(const float* __restrict__ part,
                                                    float* __restrict__ out) {
  int i = blockIdx.x * 256 + threadIdx.x;
  if (i >= B_ * NC_) return;
  float s = 0.f;
#pragma unroll 8
  for (int kc = 0; kc < NKC; ++kc) s += part[(size_t)kc * (B_ * NC_) + i];
  out[i] = s;
}

// ---------------------------------------------------------------------------
extern "C" void kernel_launch(void* const* d_in, const int* in_sizes, int n_in,
                              void* d_out, int out_size, void* d_ws, size_t ws_size,
                              hipStream_t stream) {
  const float* x_tokens = (const float*)d_in[0];
  const float* attn     = (const float*)d_in[1];
  const float* w1 = (const float*)d_in[2];
  const float* b1 = (const float*)d_in[3];
  const float* w2 = (const float*)d_in[4];
  const float* b2 = (const float*)d_in[5];
  const float* w3 = (const float*)d_in[6];
  const float* b3 = (const float*)d_in[7];
  const float* w4 = (const float*)d_in[8];
  const float* b4 = (const float*)d_in[9];
  const float* proto_l = (const float*)d_in[10];
  const float* proto_g = (const float*)d_in[11];
  const float* last_w  = (const float*)d_in[12];
  const float* last_wg = (const float*)d_in[13];
  float* out = (float*)d_out;

  char* wsb = (char*)d_ws;
  auto alloc = [&](size_t bytes) {
    char* p = wsb;
    wsb += (bytes + 255) & ~(size_t)255;
    return p;
  };
  // A0 region (31.5 MB) is dead after gemm1; bufB, wT2, part alias into it.
  bf16* A0   = (bf16*)alloc((size_t)M_PAD * D_IN * sizeof(bf16));   // 31.5 MB
  bf16* bufA = (bf16*)alloc((size_t)M_PAD * 384 * sizeof(bf16));    // 15.7 MB
  bf16* w1b = (bf16*)alloc((size_t)384 * 768 * sizeof(bf16));
  bf16* w2b = (bf16*)alloc((size_t)384 * 384 * sizeof(bf16));
  bf16* w3b = (bf16*)alloc((size_t)192 * 384 * sizeof(bf16));
  bf16* w4b = (bf16*)alloc((size_t)192 * 192 * sizeof(bf16));
  bf16* plb = (bf16*)alloc((size_t)PPAD * C_ * sizeof(bf16));
  int*   rowidx = (int*)  alloc((size_t)M_PAD * sizeof(int));
  float* fnorm  = (float*)alloc((size_t)M_PAD * sizeof(float));
  float* pnl    = (float*)alloc((size_t)PPAD * sizeof(float));
  float* png    = (float*)alloc((size_t)P_ * sizeof(float));
  float* actg   = (float*)alloc((size_t)B_ * P_ * sizeof(float));
  float* actl   = (float*)alloc((size_t)B_ * P_ * sizeof(float));

  // aliases inside A0's 31.5 MB (A0 dead after gemm1; all offsets checked):
  bf16*  bufB = A0;                                        // 15.7 MB used
  float* wT2  = (float*)((char*)A0 + 16 * 1024 * 1024);    // 3.2 MB
  float* part = (float*)((char*)A0 + 20 * 1024 * 1024);    // 4.1 MB (< 31.5)

  bf16* H1 = bufA;   // [M_PAD][384]
  bf16* H2 = bufB;   // [M_PAD][384]  overwrites dead A0
  bf16* H3 = bufA;   // [M_PAD][192]  (H1 dead after gemm2)
  bf16* Fb = bufB;   // [M_PAD][192]  (H2 dead after gemm3; 7.9 MB < 15.7)

  prologue<<<B_ + CVT_TOT / 256, 256, 0, stream>>>(
      attn, rowidx, w1, w2, w3, w4, proto_l, w1b, w2b, w3b, w4b, plb);

  gather_cvt<<<M_PAD, 192, 0, stream>>>(x_tokens, rowidx, A0);

  gemm_bf16<0, 128><<<dim3(M_PAD / 128, 384 / 128), 256, 0, stream>>>(
      A0, w1b, b1, H1, 384, 768);
  gemm_bf16<0, 128><<<dim3(M_PAD / 128, 384 / 128), 256, 0, stream>>>(
      H1, w2b, b2, H2, 384, 384);
  gemm_bf16<0, 64><<<dim3(M_PAD / 128, 192 / 64), 256, 0, stream>>>(
      H2, w3b, b3, H3, 192, 384);
  gemm_bf16<1, 64><<<dim3(M_PAD / 128, 192 / 64), 256, 0, stream>>>(
      H3, w4b, b4, Fb, 192, 192);

  mid_k<<<NORM_BLKS + PREP_BLKS, 256, 0, stream>>>(
      Fb, plb, proto_g, last_wg, last_w, fnorm, pnl, png, wT2);

  dist_fused<<<NIMG_BLKS + NCLS_BLKS, 256, 0, stream>>>(
      Fb, plb, fnorm, pnl, proto_g, png, actl, actg);

  final_partial<<<dim3(NKC, B_ / BT_), 256, 0, stream>>>(actg, actl, wT2, part);
  final_reduce<<<(B_ * NC_ + 255) / 256, 256, 0, stream>>>(part, out);
}